// Round 1
// baseline (707.307 us; speedup 1.0000x reference)
//
#include <hip/hip_runtime.h>
#include <math.h>

#define NN 48

__device__ __forceinline__ float sigmoidf_(float x) {
    return 1.0f / (1.0f + __expf(-x));
}

// ---------------- reductions ----------------
// r2[b,i, 2c]=max_{j!=i} x2[b,i,j,c] (with 0 folded in, matching where(m,x,0))
// r2[b,i,2c+1]=min_{j!=i} (with 1 folded in)
__global__ __launch_bounds__(256) void k_reduce2(const float* __restrict__ x2, float* __restrict__ r2) {
    int idx = blockIdx.x * 256 + threadIdx.x;
    if (idx >= 4 * NN * 16) return;
    int c = idx & 15;
    int pos = idx >> 4;            // b*48+i
    int i = pos % NN;
    float ex = 0.0f, fa = 1.0f;
    const float* base = x2 + (size_t)pos * NN * 16 + c;
    for (int j = 0; j < NN; ++j) {
        if (j == i) continue;
        float v = base[j * 16];
        ex = fmaxf(ex, v);
        fa = fminf(fa, v);
    }
    r2[pos * 32 + 2 * c] = ex;
    r2[pos * 32 + 2 * c + 1] = fa;
}

// r3[b,i,j,2c]=max_{k not in {i,j}} x3[b,i,j,k,c]; if i==j fully masked -> ex=0, fa=1
__global__ __launch_bounds__(256) void k_reduce3(const float* __restrict__ x3, float* __restrict__ r3) {
    int idx = blockIdx.x * 256 + threadIdx.x;   // < 147456
    int c = idx & 15;
    int pos = idx >> 4;            // (b*48+i)*48+j
    int j = pos % NN;
    int bi = pos / NN;
    int i = bi % NN;
    float ex = 0.0f, fa = 1.0f;
    if (i != j) {
        const float* base = x3 + (size_t)pos * NN * 16 + c;
        for (int k = 0; k < NN; ++k) {
            if (k == i || k == j) continue;
            float v = base[k * 16];
            ex = fmaxf(ex, v);
            fa = fminf(fa, v);
        }
    }
    r3[(size_t)pos * 32 + 2 * c] = ex;
    r3[(size_t)pos * 32 + 2 * c + 1] = fa;
}

// ---------------- group 0: t0=[x0(16), r1(32)] -> MLP(48->64->16), 4 rows ----------------
__global__ __launch_bounds__(64) void k_g0(const float* __restrict__ x0, const float* __restrict__ x1,
                                           const float* __restrict__ W1, const float* __restrict__ b1,
                                           const float* __restrict__ W2, const float* __restrict__ b2,
                                           float* __restrict__ out0) {
    __shared__ float st0[4][48];
    __shared__ float sh[4][64];
    int t = threadIdx.x;
    int b = t >> 4, c = t & 15;
    // r1: pure max/min over i (d=1, no masking)
    float ex = -INFINITY, fa = INFINITY;
    for (int i = 0; i < NN; ++i) {
        float v = x1[(b * NN + i) * 16 + c];
        ex = fmaxf(ex, v);
        fa = fminf(fa, v);
    }
    st0[b][c] = x0[b * 16 + c];
    st0[b][16 + 2 * c] = ex;
    st0[b][17 + 2 * c] = fa;
    __syncthreads();
    for (int bb = 0; bb < 4; ++bb) {
        float h = b1[t];
        for (int cc = 0; cc < 48; ++cc) h += st0[bb][cc] * W1[cc * 64 + t];
        sh[bb][t] = fmaxf(h, 0.0f);
    }
    __syncthreads();
    int bb = t >> 4, o = t & 15;
    float acc = b2[o];
    for (int tt = 0; tt < 64; ++tt) acc += sh[bb][tt] * W2[tt * 16 + o];
    out0[bb * 16 + o] = sigmoidf_(acc);
}

// ---------------- group 1: t1=[x0(16), x1(16), r2(32)] -> MLP(64->64->16), 192 rows ----------------
__global__ __launch_bounds__(64) void k_g1(const float* __restrict__ x0, const float* __restrict__ x1,
                                           const float* __restrict__ r2,
                                           const float* __restrict__ W1, const float* __restrict__ b1,
                                           const float* __restrict__ W2, const float* __restrict__ b2,
                                           float* __restrict__ out1) {
    __shared__ __align__(16) float sin_[64];
    __shared__ float sh[64];
    int row = blockIdx.x;          // b*48+i
    int b = row / NN;
    int ln = threadIdx.x;
    float v;
    if (ln < 16)      v = x0[b * 16 + ln];
    else if (ln < 32) v = x1[row * 16 + (ln - 16)];
    else              v = r2[row * 32 + (ln - 32)];
    sin_[ln] = v;
    __syncthreads();
    float h = b1[ln];
    #pragma unroll
    for (int c4 = 0; c4 < 64; c4 += 4) {
        float4 iv = *(const float4*)&sin_[c4];
        h += iv.x * W1[(c4 + 0) * 64 + ln] + iv.y * W1[(c4 + 1) * 64 + ln]
           + iv.z * W1[(c4 + 2) * 64 + ln] + iv.w * W1[(c4 + 3) * 64 + ln];
    }
    sh[ln] = fmaxf(h, 0.0f);
    __syncthreads();
    if (ln < 16) {
        float acc = b2[ln];
        #pragma unroll
        for (int tt = 0; tt < 64; ++tt) acc += sh[tt] * W2[tt * 16 + ln];
        out1[row * 16 + ln] = sigmoidf_(acc);
    }
}

// ---------------- group 2: t2p[b,i,j] = [chunk(i,j), chunk(j,i)] -> MLP(128->64->16), 9216 rows
// chunk(a1,a2) = [x1[b,a1](16), x2[b,a1,a2](16), r3[b,a1,a2](32)]
__global__ __launch_bounds__(256) void k_g2(const float* __restrict__ x1, const float* __restrict__ x2,
                                            const float* __restrict__ r3,
                                            const float* __restrict__ W1, const float* __restrict__ b1,
                                            const float* __restrict__ W2, const float* __restrict__ b2,
                                            float* __restrict__ out2) {
    __shared__ __align__(16) float sW1[128 * 64];
    __shared__ __align__(16) float sin_[4][128];
    __shared__ float sh[4][64];
    int tid = threadIdx.x;
    int wv = tid >> 6, ln = tid & 63;
    for (int p = tid; p < 128 * 64; p += 256) sW1[p] = W1[p];
    float bias = b1[ln];
    __syncthreads();
    for (int rr = 0; rr < 4; ++rr) {
        int row = blockIdx.x * 16 + rr * 4 + wv;    // (b*48+i)*48+j
        int j = row % NN;
        int bi = row / NN;
        int i = bi % NN;
        int b = bi / NN;
        for (int cc = ln; cc < 128; cc += 64) {
            int half = cc >> 6, w = cc & 63;
            int a1 = half ? j : i;
            int a2 = half ? i : j;
            float v;
            if (w < 16)      v = x1[(b * NN + a1) * 16 + w];
            else if (w < 32) v = x2[((b * NN + a1) * NN + a2) * 16 + (w - 16)];
            else             v = r3[((size_t)(b * NN + a1) * NN + a2) * 32 + (w - 32)];
            sin_[wv][cc] = v;
        }
        __syncthreads();
        float h = bias;
        #pragma unroll
        for (int c4 = 0; c4 < 128; c4 += 4) {
            float4 iv = *(const float4*)&sin_[wv][c4];
            h += iv.x * sW1[(c4 + 0) * 64 + ln] + iv.y * sW1[(c4 + 1) * 64 + ln]
               + iv.z * sW1[(c4 + 2) * 64 + ln] + iv.w * sW1[(c4 + 3) * 64 + ln];
        }
        sh[wv][ln] = fmaxf(h, 0.0f);
        __syncthreads();
        if (ln < 16) {
            float acc = b2[ln];
            #pragma unroll
            for (int tt = 0; tt < 64; ++tt) acc += sh[wv][tt] * W2[tt * 16 + ln];
            out2[row * 16 + ln] = sigmoidf_(acc);
        }
        __syncthreads();
    }
}

// ---------------- group 3: 6-permutation chunks -> MLP(192->64->16), 442368 rows
// t3p[b,i,j,k] = concat over orderings (i,j,k),(i,k,j),(j,i,k),(k,i,j),(j,k,i),(k,j,i)
//   of u(a1,a2,a3) = [x2[b,a1,a2](16), x3[b,a1,a2,a3](16)]
// One block per (b,i,j) triple; 4 chunks of 12 k-rows; wave wv computes rows wv*3..wv*3+2.
__global__ __launch_bounds__(256) void k_g3(const float* __restrict__ x2, const float* __restrict__ x3,
                                            const float* __restrict__ W1, const float* __restrict__ b1,
                                            const float* __restrict__ W2, const float* __restrict__ b2,
                                            float* __restrict__ out3) {
    __shared__ __align__(16) float sW1[192 * 64];   // 48 KB
    __shared__ __align__(16) float sin_[12][192];   // 9 KB
    __shared__ float sh[12][65];                    // 3.05 KB (pad 65 breaks layer-2 bank conflicts)

    int tid = threadIdx.x;
    int wv = tid >> 6, ln = tid & 63;
    int triple = blockIdx.x;                        // (b*48+i)*48+j
    int j = triple % NN;
    int bi = triple / NN;
    int i = bi % NN;
    int b = bi / NN;

    for (int p = tid; p < 192 * 64; p += 256) sW1[p] = W1[p];

    const int x2b = (b * NN) * NN * 16;
    const int x3b = ((b * NN) * NN) * NN * 16;
    float bias = b1[ln];

    for (int chn = 0; chn < 4; ++chn) {
        __syncthreads();   // covers weight staging (first iter) and sin_/sh reuse
        // build 12 rows x 192 channels
        for (int p = tid; p < 12 * 192; p += 256) {
            int r = p / 192;
            int cc = p - r * 192;
            int k = chn * 12 + r;
            int chunk = cc >> 5, w = cc & 31;
            int a1, a2, a3;
            switch (chunk) {
                case 0:  a1 = i; a2 = j; a3 = k; break;
                case 1:  a1 = i; a2 = k; a3 = j; break;
                case 2:  a1 = j; a2 = i; a3 = k; break;
                case 3:  a1 = k; a2 = i; a3 = j; break;
                case 4:  a1 = j; a2 = k; a3 = i; break;
                default: a1 = k; a2 = j; a3 = i; break;
            }
            float v;
            if (w < 16) v = x2[x2b + (a1 * NN + a2) * 16 + w];
            else        v = x3[x3b + ((a1 * NN + a2) * NN + a3) * 16 + (w - 16)];
            sin_[r][cc] = v;
        }
        __syncthreads();

        // layer 1: lane ln owns h-column ln; 3 rows per lane; weights pass-resident in registers
        int r0 = wv * 3;
        float h0 = bias, h1 = bias, h2 = bias;
        for (int ps = 0; ps < 4; ++ps) {
            float w_[48];
            #pragma unroll
            for (int cc = 0; cc < 48; ++cc) w_[cc] = sW1[(ps * 48 + cc) * 64 + ln];
            #pragma unroll
            for (int c4 = 0; c4 < 48; c4 += 4) {
                float4 i0 = *(const float4*)&sin_[r0 + 0][ps * 48 + c4];
                float4 i1 = *(const float4*)&sin_[r0 + 1][ps * 48 + c4];
                float4 i2 = *(const float4*)&sin_[r0 + 2][ps * 48 + c4];
                h0 += i0.x * w_[c4] + i0.y * w_[c4 + 1] + i0.z * w_[c4 + 2] + i0.w * w_[c4 + 3];
                h1 += i1.x * w_[c4] + i1.y * w_[c4 + 1] + i1.z * w_[c4 + 2] + i1.w * w_[c4 + 3];
                h2 += i2.x * w_[c4] + i2.y * w_[c4 + 1] + i2.z * w_[c4 + 2] + i2.w * w_[c4 + 3];
            }
        }
        sh[r0 + 0][ln] = fmaxf(h0, 0.0f);
        sh[r0 + 1][ln] = fmaxf(h1, 0.0f);
        sh[r0 + 2][ln] = fmaxf(h2, 0.0f);
        __syncthreads();

        // layer 2: 12 rows x 16 outs
        if (tid < 192) {
            int r = tid >> 4, o = tid & 15;
            float acc = b2[o];
            #pragma unroll
            for (int tt = 0; tt < 64; ++tt) acc += sh[r][tt] * W2[tt * 16 + o];
            int k = chn * 12 + r;
            out3[((size_t)triple * NN + k) * 16 + o] = sigmoidf_(acc);
        }
    }
}

extern "C" void kernel_launch(void* const* d_in, const int* in_sizes, int n_in,
                              void* d_out, int out_size, void* d_ws, size_t ws_size,
                              hipStream_t stream) {
    const float* x0 = (const float*)d_in[0];
    const float* x1 = (const float*)d_in[1];
    const float* x2 = (const float*)d_in[2];
    const float* x3 = (const float*)d_in[3];
    const float* W1_0 = (const float*)d_in[4];
    const float* b1_0 = (const float*)d_in[5];
    const float* W2_0 = (const float*)d_in[6];
    const float* b2_0 = (const float*)d_in[7];
    const float* W1_1 = (const float*)d_in[8];
    const float* b1_1 = (const float*)d_in[9];
    const float* W2_1 = (const float*)d_in[10];
    const float* b2_1 = (const float*)d_in[11];
    const float* W1_2 = (const float*)d_in[12];
    const float* b1_2 = (const float*)d_in[13];
    const float* W2_2 = (const float*)d_in[14];
    const float* b2_2 = (const float*)d_in[15];
    const float* W1_3 = (const float*)d_in[16];
    const float* b1_3 = (const float*)d_in[17];
    const float* W2_3 = (const float*)d_in[18];
    const float* b2_3 = (const float*)d_in[19];

    float* out = (float*)d_out;
    float* r2 = (float*)d_ws;                 // 4*48*32     = 6144 floats
    float* r3 = r2 + 6144;                    // 4*48*48*32  = 294912 floats  (~1.2 MB total)

    hipLaunchKernelGGL(k_reduce2, dim3(12), dim3(256), 0, stream, x2, r2);
    hipLaunchKernelGGL(k_reduce3, dim3(576), dim3(256), 0, stream, x3, r3);
    hipLaunchKernelGGL(k_g0, dim3(1), dim3(64), 0, stream, x0, x1, W1_0, b1_0, W2_0, b2_0, out);
    hipLaunchKernelGGL(k_g1, dim3(192), dim3(64), 0, stream, x0, x1, r2, W1_1, b1_1, W2_1, b2_1, out + 64);
    hipLaunchKernelGGL(k_g2, dim3(576), dim3(256), 0, stream, x1, x2, r3, W1_2, b1_2, W2_2, b2_2, out + 3136);
    hipLaunchKernelGGL(k_g3, dim3(9216), dim3(256), 0, stream, x2, x3, W1_3, b1_3, W2_3, b2_3, out + 150592);
}

// Round 2
// 153.975 us; speedup vs baseline: 4.5936x; 4.5936x over previous
//
#include <hip/hip_runtime.h>
#include <math.h>

#define NN 48

typedef __attribute__((ext_vector_type(8))) short bf16x8;
typedef __attribute__((ext_vector_type(4))) float f32x4;

__device__ __forceinline__ float sigmoidf_(float x) {
    return 1.0f / (1.0f + __expf(-x));
}

__device__ __forceinline__ unsigned short f2bf(float f) {
    unsigned u = __float_as_uint(f);
    unsigned r = (u + 0x7fffu + ((u >> 16) & 1u)) >> 16;
    return (unsigned short)r;
}

// ---------------- reductions ----------------
__global__ __launch_bounds__(256) void k_reduce2(const float* __restrict__ x2, float* __restrict__ r2) {
    int idx = blockIdx.x * 256 + threadIdx.x;
    if (idx >= 4 * NN * 16) return;
    int c = idx & 15;
    int pos = idx >> 4;            // b*48+i
    int i = pos % NN;
    float ex = 0.0f, fa = 1.0f;
    const float* base = x2 + (size_t)pos * NN * 16 + c;
    for (int j = 0; j < NN; ++j) {
        if (j == i) continue;
        float v = base[j * 16];
        ex = fmaxf(ex, v);
        fa = fminf(fa, v);
    }
    r2[pos * 32 + 2 * c] = ex;
    r2[pos * 32 + 2 * c + 1] = fa;
}

__global__ __launch_bounds__(256) void k_reduce3(const float* __restrict__ x3, float* __restrict__ r3) {
    int idx = blockIdx.x * 256 + threadIdx.x;   // < 147456
    int c = idx & 15;
    int pos = idx >> 4;            // (b*48+i)*48+j
    int j = pos % NN;
    int bi = pos / NN;
    int i = bi % NN;
    float ex = 0.0f, fa = 1.0f;
    if (i != j) {
        const float* base = x3 + (size_t)pos * NN * 16 + c;
        for (int k = 0; k < NN; ++k) {
            if (k == i || k == j) continue;
            float v = base[k * 16];
            ex = fmaxf(ex, v);
            fa = fminf(fa, v);
        }
    }
    r3[(size_t)pos * 32 + 2 * c] = ex;
    r3[(size_t)pos * 32 + 2 * c + 1] = fa;
}

// ---------------- group 0 ----------------
__global__ __launch_bounds__(64) void k_g0(const float* __restrict__ x0, const float* __restrict__ x1,
                                           const float* __restrict__ W1, const float* __restrict__ b1,
                                           const float* __restrict__ W2, const float* __restrict__ b2,
                                           float* __restrict__ out0) {
    __shared__ float st0[4][48];
    __shared__ float sh[4][64];
    int t = threadIdx.x;
    int b = t >> 4, c = t & 15;
    float ex = -INFINITY, fa = INFINITY;
    for (int i = 0; i < NN; ++i) {
        float v = x1[(b * NN + i) * 16 + c];
        ex = fmaxf(ex, v);
        fa = fminf(fa, v);
    }
    st0[b][c] = x0[b * 16 + c];
    st0[b][16 + 2 * c] = ex;
    st0[b][17 + 2 * c] = fa;
    __syncthreads();
    for (int bb = 0; bb < 4; ++bb) {
        float h = b1[t];
        for (int cc = 0; cc < 48; ++cc) h += st0[bb][cc] * W1[cc * 64 + t];
        sh[bb][t] = fmaxf(h, 0.0f);
    }
    __syncthreads();
    int bb = t >> 4, o = t & 15;
    float acc = b2[o];
    for (int tt = 0; tt < 64; ++tt) acc += sh[bb][tt] * W2[tt * 16 + o];
    out0[bb * 16 + o] = sigmoidf_(acc);
}

// ---------------- group 1 ----------------
__global__ __launch_bounds__(64) void k_g1(const float* __restrict__ x0, const float* __restrict__ x1,
                                           const float* __restrict__ r2,
                                           const float* __restrict__ W1, const float* __restrict__ b1,
                                           const float* __restrict__ W2, const float* __restrict__ b2,
                                           float* __restrict__ out1) {
    __shared__ __align__(16) float sin_[64];
    __shared__ float sh[64];
    int row = blockIdx.x;          // b*48+i
    int b = row / NN;
    int ln = threadIdx.x;
    float v;
    if (ln < 16)      v = x0[b * 16 + ln];
    else if (ln < 32) v = x1[row * 16 + (ln - 16)];
    else              v = r2[row * 32 + (ln - 32)];
    sin_[ln] = v;
    __syncthreads();
    float h = b1[ln];
    #pragma unroll
    for (int c4 = 0; c4 < 64; c4 += 4) {
        float4 iv = *(const float4*)&sin_[c4];
        h += iv.x * W1[(c4 + 0) * 64 + ln] + iv.y * W1[(c4 + 1) * 64 + ln]
           + iv.z * W1[(c4 + 2) * 64 + ln] + iv.w * W1[(c4 + 3) * 64 + ln];
    }
    sh[ln] = fmaxf(h, 0.0f);
    __syncthreads();
    if (ln < 16) {
        float acc = b2[ln];
        #pragma unroll
        for (int tt = 0; tt < 64; ++tt) acc += sh[tt] * W2[tt * 16 + ln];
        out1[row * 16 + ln] = sigmoidf_(acc);
    }
}

// ---------------- group 2 (VALU, unchanged) ----------------
__global__ __launch_bounds__(256) void k_g2(const float* __restrict__ x1, const float* __restrict__ x2,
                                            const float* __restrict__ r3,
                                            const float* __restrict__ W1, const float* __restrict__ b1,
                                            const float* __restrict__ W2, const float* __restrict__ b2,
                                            float* __restrict__ out2) {
    __shared__ __align__(16) float sW1[128 * 64];
    __shared__ __align__(16) float sin_[4][128];
    __shared__ float sh[4][64];
    int tid = threadIdx.x;
    int wv = tid >> 6, ln = tid & 63;
    for (int p = tid; p < 128 * 64; p += 256) sW1[p] = W1[p];
    float bias = b1[ln];
    __syncthreads();
    for (int rr = 0; rr < 4; ++rr) {
        int row = blockIdx.x * 16 + rr * 4 + wv;    // (b*48+i)*48+j
        int j = row % NN;
        int bi = row / NN;
        int i = bi % NN;
        int b = bi / NN;
        for (int cc = ln; cc < 128; cc += 64) {
            int half = cc >> 6, w = cc & 63;
            int a1 = half ? j : i;
            int a2 = half ? i : j;
            float v;
            if (w < 16)      v = x1[(b * NN + a1) * 16 + w];
            else if (w < 32) v = x2[((b * NN + a1) * NN + a2) * 16 + (w - 16)];
            else             v = r3[((size_t)(b * NN + a1) * NN + a2) * 32 + (w - 32)];
            sin_[wv][cc] = v;
        }
        __syncthreads();
        float h = bias;
        #pragma unroll
        for (int c4 = 0; c4 < 128; c4 += 4) {
            float4 iv = *(const float4*)&sin_[wv][c4];
            h += iv.x * sW1[(c4 + 0) * 64 + ln] + iv.y * sW1[(c4 + 1) * 64 + ln]
               + iv.z * sW1[(c4 + 2) * 64 + ln] + iv.w * sW1[(c4 + 3) * 64 + ln];
        }
        sh[wv][ln] = fmaxf(h, 0.0f);
        __syncthreads();
        if (ln < 16) {
            float acc = b2[ln];
            #pragma unroll
            for (int tt = 0; tt < 64; ++tt) acc += sh[wv][tt] * W2[tt * 16 + ln];
            out2[row * 16 + ln] = sigmoidf_(acc);
        }
        __syncthreads();
    }
}

// ---------------- group-3 weight prep: fp32 -> bf16 MFMA B-fragments ----------------
// w1frag: [nt(4)][ks(6)][lane(64)][idx(8)]  = W1[ks*32 + (lane>>4)*8 + idx][nt*16 + (lane&15)]
// w2frag: [ks(2)][lane(64)][idx(8)]         = W2[ks*32 + (lane>>4)*8 + idx][lane&15]
__global__ __launch_bounds__(256) void k_prep3(const float* __restrict__ W1, const float* __restrict__ W2,
                                               unsigned short* __restrict__ wf) {
    int e = blockIdx.x * 256 + threadIdx.x;
    if (e >= 13312) return;
    if (e < 12288) {
        int idx = e & 7;
        int l = (e >> 3) & 63;
        int r = e >> 9;           // nt*6+ks
        int ks = r % 6, nt = r / 6;
        int cin = ks * 32 + ((l >> 4) << 3) + idx;
        int hc = (nt << 4) + (l & 15);
        wf[e] = f2bf(W1[cin * 64 + hc]);
    } else {
        int e2 = e - 12288;
        int idx = e2 & 7;
        int l = (e2 >> 3) & 63;
        int ks = e2 >> 9;
        int cin = ks * 32 + ((l >> 4) << 3) + idx;
        int o = l & 15;
        wf[e] = f2bf(W2[cin * 16 + o]);
    }
}

// ---------------- group 3: MFMA version ----------------
// One block per (b,i,j) triple. 48 k-rows -> 3 M-tiles of 16. Input 192 ch -> 6 K-steps.
// Wave wv owns h N-tile wv (16 cols). LDS A staged directly in fragment order (linear reads).
__global__ __launch_bounds__(256) void k_g3m(const float* __restrict__ x2, const float* __restrict__ x3,
                                             const unsigned short* __restrict__ wf,
                                             const float* __restrict__ b1, const float* __restrict__ b2,
                                             float* __restrict__ out3) {
    __shared__ __align__(16) unsigned short sA[3 * 6 * 64 * 8];   // 18 KB, [mt][ks][lane][8]
    __shared__ __align__(16) unsigned short sH[3 * 2 * 64 * 8];   // 6 KB,  [mt][ks][lane][8]

    int tid = threadIdx.x;
    int wv = tid >> 6, l = tid & 63;
    int triple = blockIdx.x;                        // (b*48+i)*48+j
    int j = triple % NN;
    int bi = triple / NN;
    int i = bi % NN;
    int b = bi / NN;

    // resident B fragments
    bf16x8 w1f[6];
    #pragma unroll
    for (int ks = 0; ks < 6; ++ks)
        w1f[ks] = *(const bf16x8*)(wf + (((wv * 6 + ks) << 6) + l) * 8);
    bf16x8 w2f[2];
    #pragma unroll
    for (int ks = 0; ks < 2; ++ks)
        w2f[ks] = *(const bf16x8*)(wf + 12288 + (((ks) << 6) + l) * 8);

    const int x2b = (b * NN) * NN * 16;
    const int x3b = ((b * NN) * NN) * NN * 16;

    // ---- stage 48 rows x 192 ch into A-fragment order (bf16) ----
    // task t: kk = t/48 (k index), g = t%48 (4-channel group); ks = g>>3; w = (g&7)*4
    #pragma unroll
    for (int it = 0; it < 9; ++it) {
        int t = tid + it * 256;
        int kk = t / 48;
        int g = t - kk * 48;
        int ks = g >> 3;
        int w = (g & 7) << 2;
        int a1, a2, a3;
        switch (ks) {
            case 0:  a1 = i;  a2 = j;  a3 = kk; break;
            case 1:  a1 = i;  a2 = kk; a3 = j;  break;
            case 2:  a1 = j;  a2 = i;  a3 = kk; break;
            case 3:  a1 = kk; a2 = i;  a3 = j;  break;
            case 4:  a1 = j;  a2 = kk; a3 = i;  break;
            default: a1 = kk; a2 = j;  a3 = i;  break;
        }
        const float* src;
        if (w < 16) src = x2 + x2b + (a1 * NN + a2) * 16 + w;
        else        src = x3 + x3b + ((a1 * NN + a2) * NN + a3) * 16 + (w - 16);
        float4 v = *(const float4*)src;
        ushort4 p;
        p.x = f2bf(v.x); p.y = f2bf(v.y); p.z = f2bf(v.z); p.w = f2bf(v.w);
        int mt = kk >> 4;
        int lp = (kk & 15) + ((w >> 3) << 4);
        int idx = w & 7;                         // 0 or 4
        *(ushort4*)&sA[((((mt * 6 + ks) << 6) + lp) << 3) + idx] = p;
    }
    __syncthreads();

    // ---- layer 1: wave wv = N-tile wv; 3 M-tiles x 6 K-steps ----
    float bv = b1[(wv << 4) + (l & 15)];
    f32x4 acc0 = {bv, bv, bv, bv};
    f32x4 acc1 = acc0, acc2 = acc0;
    #pragma unroll
    for (int ks = 0; ks < 6; ++ks) {
        bf16x8 a0 = *(const bf16x8*)&sA[(((0 * 6 + ks) << 6) + l) << 3];
        bf16x8 a1_ = *(const bf16x8*)&sA[(((1 * 6 + ks) << 6) + l) << 3];
        bf16x8 a2_ = *(const bf16x8*)&sA[(((2 * 6 + ks) << 6) + l) << 3];
        acc0 = __builtin_amdgcn_mfma_f32_16x16x32_bf16(a0, w1f[ks], acc0, 0, 0, 0);
        acc1 = __builtin_amdgcn_mfma_f32_16x16x32_bf16(a1_, w1f[ks], acc1, 0, 0, 0);
        acc2 = __builtin_amdgcn_mfma_f32_16x16x32_bf16(a2_, w1f[ks], acc2, 0, 0, 0);
    }

    // ---- ReLU -> bf16 -> sH in layer-2 A-fragment order ----
    // C layout: h[row = (l>>4)*4+rg + 16*mt][hc = wv*16 + (l&15)]
    {
        int within = ((wv & 1) << 4) + (l & 15);   // hc & 31
        int ks2 = wv >> 1;                         // hc >> 5
        int lhi = (within >> 3) << 4;
        int idx = within & 7;
        int rbase = (l >> 4) << 2;
        #pragma unroll
        for (int mt = 0; mt < 3; ++mt) {
            f32x4 a = (mt == 0) ? acc0 : (mt == 1) ? acc1 : acc2;
            #pragma unroll
            for (int rg = 0; rg < 4; ++rg) {
                float h = fmaxf(a[rg], 0.0f);
                int lp = rbase + rg + lhi;
                sH[((((mt << 1) + ks2) << 6) + lp) * 8 + idx] = f2bf(h);
            }
        }
    }
    __syncthreads();

    // ---- layer 2: waves 0-2, M-tile = wv ----
    if (wv < 3) {
        int mt = wv;
        float bv2 = b2[l & 15];
        f32x4 acc = {bv2, bv2, bv2, bv2};
        #pragma unroll
        for (int ks = 0; ks < 2; ++ks) {
            bf16x8 a = *(const bf16x8*)&sH[((((mt << 1) + ks) << 6) + l) << 3];
            acc = __builtin_amdgcn_mfma_f32_16x16x32_bf16(a, w2f[ks], acc, 0, 0, 0);
        }
        size_t obase = ((size_t)triple * NN + (mt << 4) + ((l >> 4) << 2)) * 16 + (l & 15);
        #pragma unroll
        for (int rg = 0; rg < 4; ++rg)
            out3[obase + (size_t)rg * 16] = sigmoidf_(acc[rg]);
    }
}

extern "C" void kernel_launch(void* const* d_in, const int* in_sizes, int n_in,
                              void* d_out, int out_size, void* d_ws, size_t ws_size,
                              hipStream_t stream) {
    const float* x0 = (const float*)d_in[0];
    const float* x1 = (const float*)d_in[1];
    const float* x2 = (const float*)d_in[2];
    const float* x3 = (const float*)d_in[3];
    const float* W1_0 = (const float*)d_in[4];
    const float* b1_0 = (const float*)d_in[5];
    const float* W2_0 = (const float*)d_in[6];
    const float* b2_0 = (const float*)d_in[7];
    const float* W1_1 = (const float*)d_in[8];
    const float* b1_1 = (const float*)d_in[9];
    const float* W2_1 = (const float*)d_in[10];
    const float* b2_1 = (const float*)d_in[11];
    const float* W1_2 = (const float*)d_in[12];
    const float* b1_2 = (const float*)d_in[13];
    const float* W2_2 = (const float*)d_in[14];
    const float* b2_2 = (const float*)d_in[15];
    const float* W1_3 = (const float*)d_in[16];
    const float* b1_3 = (const float*)d_in[17];
    const float* W2_3 = (const float*)d_in[18];
    const float* b2_3 = (const float*)d_in[19];

    float* out = (float*)d_out;
    float* r2 = (float*)d_ws;                       // 6144 floats
    float* r3 = r2 + 6144;                          // 294912 floats
    unsigned short* wf = (unsigned short*)(r3 + 294912);  // 13312 bf16 (26.6 KB)

    hipLaunchKernelGGL(k_prep3, dim3(52), dim3(256), 0, stream, W1_3, W2_3, wf);
    hipLaunchKernelGGL(k_reduce2, dim3(12), dim3(256), 0, stream, x2, r2);
    hipLaunchKernelGGL(k_reduce3, dim3(576), dim3(256), 0, stream, x3, r3);
    hipLaunchKernelGGL(k_g0, dim3(1), dim3(64), 0, stream, x0, x1, W1_0, b1_0, W2_0, b2_0, out);
    hipLaunchKernelGGL(k_g1, dim3(192), dim3(64), 0, stream, x0, x1, r2, W1_1, b1_1, W2_1, b2_1, out + 64);
    hipLaunchKernelGGL(k_g2, dim3(576), dim3(256), 0, stream, x1, x2, r3, W1_2, b1_2, W2_2, b2_2, out + 3136);
    hipLaunchKernelGGL(k_g3m, dim3(9216), dim3(256), 0, stream, x2, x3, wf, b1_3, b2_3, out + 150592);
}

// Round 4
// 94.035 us; speedup vs baseline: 7.5218x; 1.6374x over previous
//
#include <hip/hip_runtime.h>
#include <math.h>

#define NN 48

typedef __attribute__((ext_vector_type(8))) short bf16x8;
typedef __attribute__((ext_vector_type(4))) float f32x4;

__device__ __forceinline__ float sigmoidf_(float x) {
    return 1.0f / (1.0f + __expf(-x));
}

__device__ __forceinline__ unsigned short f2bf(float f) {
    unsigned u = __float_as_uint(f);
    return (unsigned short)((u + 0x7fffu + ((u >> 16) & 1u)) >> 16);
}

__device__ __forceinline__ unsigned packbf2(float a, float b) {
    return (unsigned)f2bf(a) | ((unsigned)f2bf(b) << 16);
}

// ================= kernel A: weight prep (block 0) + reduce3 (blocks 1..144) =================
// wf layout: w1frag [nt(4)][ks(6)][lane(64)][8] then w2frag [ks(2)][lane(64)][8]
// r3[pos][2c]=max_{k not in {i,j}} x3[pos,k,c] (0-folded), [2c+1]=min (1-folded); i==j -> 0/1.
__global__ __launch_bounds__(256) void k_pre(const float* __restrict__ x3,
                                             const float* __restrict__ W1, const float* __restrict__ W2,
                                             float* __restrict__ r3, unsigned short* __restrict__ wf) {
    int tid = threadIdx.x;
    if (blockIdx.x == 0) {
        for (int e = tid; e < 13312; e += 256) {
            unsigned short v;
            if (e < 12288) {
                int idx = e & 7, l = (e >> 3) & 63, r = e >> 9;   // r = nt*6+ks
                int ks = r % 6, nt = r / 6;
                v = f2bf(W1[(ks * 32 + ((l >> 4) << 3) + idx) * 64 + (nt << 4) + (l & 15)]);
            } else {
                int e2 = e - 12288;
                int idx = e2 & 7, l = (e2 >> 3) & 63, ks = e2 >> 9;
                v = f2bf(W2[(ks * 32 + ((l >> 4) << 3) + idx) * 16 + (l & 15)]);
            }
            wf[e] = v;
        }
        return;
    }
    int idx = (blockIdx.x - 1) * 256 + tid;          // < 36864
    int cq = idx & 3;                                 // channel quad
    int pos = idx >> 2;                               // (b*48+i)*48+j
    int j = pos % NN;
    int i = (pos / NN) % NN;
    const float* base = x3 + (size_t)pos * NN * 16 + (cq << 2);
    float4 ex = make_float4(0.f, 0.f, 0.f, 0.f);
    float4 fa = make_float4(1.f, 1.f, 1.f, 1.f);
    bool dead = (i == j);
    #pragma unroll 8
    for (int k = 0; k < NN; ++k) {
        float4 v = *(const float4*)(base + k * 16);
        bool ok = !dead && (k != i) && (k != j);
        ex.x = fmaxf(ex.x, ok ? v.x : 0.f);  fa.x = fminf(fa.x, ok ? v.x : 1.f);
        ex.y = fmaxf(ex.y, ok ? v.y : 0.f);  fa.y = fminf(fa.y, ok ? v.y : 1.f);
        ex.z = fmaxf(ex.z, ok ? v.z : 0.f);  fa.z = fminf(fa.z, ok ? v.z : 1.f);
        ex.w = fmaxf(ex.w, ok ? v.w : 0.f);  fa.w = fminf(fa.w, ok ? v.w : 1.f);
    }
    float* dst = r3 + (size_t)pos * 32 + (cq << 3);
    *(float4*)dst       = make_float4(ex.x, fa.x, ex.y, fa.y);
    *(float4*)(dst + 4) = make_float4(ex.z, fa.z, ex.w, fa.w);
}

// ================= kernel B: g0 (block 0) + g1 w/ fused reduce2 (1..48) + g2 (49..624) ==========
__global__ __launch_bounds__(256) void k_small(const float* __restrict__ x0, const float* __restrict__ x1,
        const float* __restrict__ x2, const float* __restrict__ r3,
        const float* __restrict__ W1_0, const float* __restrict__ b1_0,
        const float* __restrict__ W2_0, const float* __restrict__ b2_0,
        const float* __restrict__ W1_1, const float* __restrict__ b1_1,
        const float* __restrict__ W2_1, const float* __restrict__ b2_1,
        const float* __restrict__ W1_2, const float* __restrict__ b1_2,
        const float* __restrict__ W2_2, const float* __restrict__ b2_2,
        float* __restrict__ out) {
    __shared__ __align__(16) float smem[8960];       // g2: 8192 + 512 + 256
    int tid = threadIdx.x;
    int blk = blockIdx.x;
    if (blk == 0) {
        // ---- group 0: t0=[x0(16), r1(32)] -> MLP(48->64->16), 4 rows ----
        float* st0 = smem;            // [4][48]
        float* sh0 = smem + 192;      // [4][64]
        int b = tid >> 6, sub = (tid >> 4) & 3, c = tid & 15;
        float ex = -INFINITY, fa = INFINITY;       // d=1 reduce: no masking
        for (int ii = sub * 12; ii < sub * 12 + 12; ++ii) {
            float v = x1[(b * NN + ii) * 16 + c];
            ex = fmaxf(ex, v); fa = fminf(fa, v);
        }
        ex = fmaxf(ex, __shfl_xor(ex, 16)); fa = fminf(fa, __shfl_xor(fa, 16));
        ex = fmaxf(ex, __shfl_xor(ex, 32)); fa = fminf(fa, __shfl_xor(fa, 32));
        if (sub == 0) { st0[b * 48 + 16 + 2 * c] = ex; st0[b * 48 + 17 + 2 * c] = fa; }
        if (tid < 64) st0[(tid >> 4) * 48 + (tid & 15)] = x0[tid];
        __syncthreads();
        {
            int bb = tid >> 6, ln = tid & 63;
            float h = b1_0[ln];
            for (int cc = 0; cc < 48; ++cc) h += st0[bb * 48 + cc] * W1_0[cc * 64 + ln];
            sh0[bb * 64 + ln] = fmaxf(h, 0.f);
        }
        __syncthreads();
        if (tid < 64) {
            int bb = tid >> 4, o = tid & 15;
            float acc = b2_0[o];
            for (int tt = 0; tt < 64; ++tt) acc += sh0[bb * 64 + tt] * W2_0[tt * 16 + o];
            out[bb * 16 + o] = sigmoidf_(acc);
        }
    } else if (blk <= 48) {
        // ---- group 1: t1=[x0(16), x1(16), r2(32)] -> MLP(64->64->16); 4 rows/block ----
        int grp = tid >> 6, ln = tid & 63;
        int row = (blk - 1) * 4 + grp;             // b*48+i, < 192
        int b = row / NN, i = row % NN;
        float* sin1 = smem + grp * 64;
        float* sh1  = smem + 256 + grp * 64;
        int c = ln & 15, q = ln >> 4;
        float ex = 0.f, fa = 1.f;                  // d=2 reduce: 0/1-folded
        const float* xb = x2 + (size_t)row * NN * 16 + c;
        for (int jj = q * 12; jj < q * 12 + 12; ++jj) {
            float v = xb[jj * 16];
            bool ok = (jj != i);
            ex = fmaxf(ex, ok ? v : 0.f); fa = fminf(fa, ok ? v : 1.f);
        }
        ex = fmaxf(ex, __shfl_xor(ex, 16)); fa = fminf(fa, __shfl_xor(fa, 16));
        ex = fmaxf(ex, __shfl_xor(ex, 32)); fa = fminf(fa, __shfl_xor(fa, 32));
        if (q == 0) { sin1[32 + 2 * c] = ex; sin1[33 + 2 * c] = fa; }
        if (ln < 16) sin1[ln] = x0[b * 16 + ln];
        else if (ln < 32) sin1[ln] = x1[row * 16 + (ln - 16)];
        __syncthreads();
        float h = b1_1[ln];
        #pragma unroll
        for (int c4 = 0; c4 < 64; c4 += 4) {
            float4 iv = *(const float4*)&sin1[c4];
            h += iv.x * W1_1[(c4 + 0) * 64 + ln] + iv.y * W1_1[(c4 + 1) * 64 + ln]
               + iv.z * W1_1[(c4 + 2) * 64 + ln] + iv.w * W1_1[(c4 + 3) * 64 + ln];
        }
        sh1[ln] = fmaxf(h, 0.f);
        __syncthreads();
        if (ln < 16) {
            float acc = b2_1[ln];
            #pragma unroll
            for (int tt = 0; tt < 64; ++tt) acc += sh1[tt] * W2_1[tt * 16 + ln];
            out[64 + row * 16 + ln] = sigmoidf_(acc);
        }
    } else {
        // ---- group 2: [chunk(i,j), chunk(j,i)] -> MLP(128->64->16), 16 rows/block ----
        float* sW1  = smem;            // 8192
        float* sin_ = smem + 8192;     // [4][128]
        float* sh   = smem + 8704;     // [4][64]
        int wv = tid >> 6, ln = tid & 63;
        for (int p = tid; p < 8192; p += 256) sW1[p] = W1_2[p];
        float bias = b1_2[ln];
        __syncthreads();
        for (int rr = 0; rr < 4; ++rr) {
            int row = (blk - 49) * 16 + rr * 4 + wv;   // (b*48+i)*48+j
            int j = row % NN;
            int bi = row / NN;
            int i = bi % NN;
            int b = bi / NN;
            for (int cc = ln; cc < 128; cc += 64) {
                int half = cc >> 6, w = cc & 63;
                int a1 = half ? j : i;
                int a2 = half ? i : j;
                float v;
                if (w < 16)      v = x1[(b * NN + a1) * 16 + w];
                else if (w < 32) v = x2[((b * NN + a1) * NN + a2) * 16 + (w - 16)];
                else             v = r3[((size_t)(b * NN + a1) * NN + a2) * 32 + (w - 32)];
                sin_[wv * 128 + cc] = v;
            }
            __syncthreads();
            float h = bias;
            #pragma unroll
            for (int c4 = 0; c4 < 128; c4 += 4) {
                float4 iv = *(const float4*)&sin_[wv * 128 + c4];
                h += iv.x * sW1[(c4 + 0) * 64 + ln] + iv.y * sW1[(c4 + 1) * 64 + ln]
                   + iv.z * sW1[(c4 + 2) * 64 + ln] + iv.w * sW1[(c4 + 3) * 64 + ln];
            }
            sh[wv * 64 + ln] = fmaxf(h, 0.f);
            __syncthreads();
            if (ln < 16) {
                float acc = b2_2[ln];
                #pragma unroll
                for (int tt = 0; tt < 64; ++tt) acc += sh[wv * 64 + tt] * W2_2[tt * 16 + ln];
                out[3136 + row * 16 + ln] = sigmoidf_(acc);
            }
            __syncthreads();
        }
    }
}

// ================= kernel C: group 3 MFMA =================
// One block per (b,i,j). 48 k-rows = 3 M-tiles; 192 ch = 6 K-steps; wave wv = h N-tile wv.
// Staging task t -> LDS byte t*8 (contiguous per wave, conflict-free); fragment id t>>7 is
// wave-uniform -> scalar switch. Same (row,channel)->LDS mapping as the verified r2 kernel.
__global__ __launch_bounds__(256) void k_g3m(const float* __restrict__ x2, const float* __restrict__ x3,
                                             const unsigned short* __restrict__ wf,
                                             const float* __restrict__ b1, const float* __restrict__ b2,
                                             float* __restrict__ out3) {
    __shared__ __align__(16) unsigned short sA[18 * 64 * 8];   // 18 KB, [f=mt*6+ks][lane][8]
    __shared__ __align__(16) unsigned short sH[6 * 64 * 8];    // 6 KB,  [mt*2+ks][lane][8]

    int tid = threadIdx.x;
    int wv = tid >> 6, l = tid & 63;
    int triple = blockIdx.x;                        // (b*48+i)*48+j
    int j = triple % NN;
    int bi = triple / NN;
    int i = bi % NN;
    int b = bi / NN;

    // resident B fragments
    bf16x8 w1f[6];
    #pragma unroll
    for (int ks = 0; ks < 6; ++ks)
        w1f[ks] = *(const bf16x8*)(wf + (((wv * 6 + ks) << 6) + l) * 8);
    bf16x8 w2f[2];
    #pragma unroll
    for (int ks = 0; ks < 2; ++ks)
        w2f[ks] = *(const bf16x8*)(wf + 12288 + ((ks << 6) + l) * 8);

    const int x2b = b * NN * NN * 16;
    const int x3b = b * NN * NN * NN * 16;

    // ---- stage 48 rows x 192 ch into A-fragment order; task t writes LDS byte t*8 ----
    #pragma unroll
    for (int it = 0; it < 9; ++it) {
        int t = it * 256 + tid;
        int fs = __builtin_amdgcn_readfirstlane(t >> 7);   // wave-uniform fragment id
        int mt = fs / 6;
        int ks = fs - mt * 6;
        int lp = (t >> 1) & 63;
        int kk = (mt << 4) + (lp & 15);
        int w = ((lp >> 4) << 3) + ((t & 1) << 2);         // channel-in-chunk, {0,4,...,28}
        int a1, a2, a3;
        switch (ks) {
            case 0:  a1 = i;  a2 = j;  a3 = kk; break;
            case 1:  a1 = i;  a2 = kk; a3 = j;  break;
            case 2:  a1 = j;  a2 = i;  a3 = kk; break;
            case 3:  a1 = kk; a2 = i;  a3 = j;  break;
            case 4:  a1 = j;  a2 = kk; a3 = i;  break;
            default: a1 = kk; a2 = j;  a3 = i;  break;
        }
        const float* p2 = x2 + x2b + (a1 * NN + a2) * 16 + w;
        const float* p3 = x3 + x3b + ((a1 * NN + a2) * NN + a3) * 16 + (w - 16);
        const float* p = (w < 16) ? p2 : p3;
        float4 v = *(const float4*)p;
        uint2 pk;
        pk.x = packbf2(v.x, v.y);
        pk.y = packbf2(v.z, v.w);
        *(uint2*)&sA[t * 4] = pk;
    }
    __syncthreads();

    // ---- layer 1: 3 M-tiles x 6 K-steps, N-tile = wv ----
    float bv = b1[(wv << 4) + (l & 15)];
    f32x4 acc0 = {bv, bv, bv, bv};
    f32x4 acc1 = acc0, acc2 = acc0;
    #pragma unroll
    for (int ks = 0; ks < 6; ++ks) {
        bf16x8 a0  = *(const bf16x8*)&sA[(((0 * 6 + ks) << 6) + l) << 3];
        bf16x8 a1_ = *(const bf16x8*)&sA[(((1 * 6 + ks) << 6) + l) << 3];
        bf16x8 a2_ = *(const bf16x8*)&sA[(((2 * 6 + ks) << 6) + l) << 3];
        acc0 = __builtin_amdgcn_mfma_f32_16x16x32_bf16(a0,  w1f[ks], acc0, 0, 0, 0);
        acc1 = __builtin_amdgcn_mfma_f32_16x16x32_bf16(a1_, w1f[ks], acc1, 0, 0, 0);
        acc2 = __builtin_amdgcn_mfma_f32_16x16x32_bf16(a2_, w1f[ks], acc2, 0, 0, 0);
    }

    // ---- ReLU -> bf16 -> sH in layer-2 A-fragment order ----
    {
        int within = ((wv & 1) << 4) + (l & 15);   // hc & 31
        int ks2 = wv >> 1;                         // hc >> 5
        int lhi = (within >> 3) << 4;
        int idx = within & 7;
        int rbase = (l >> 4) << 2;
        #pragma unroll
        for (int mt = 0; mt < 3; ++mt) {
            f32x4 a = (mt == 0) ? acc0 : (mt == 1) ? acc1 : acc2;
            #pragma unroll
            for (int rg = 0; rg < 4; ++rg) {
                float h = fmaxf(a[rg], 0.0f);
                int lp = rbase + rg + lhi;
                sH[((((mt << 1) + ks2) << 6) + lp) * 8 + idx] = f2bf(h);
            }
        }
    }
    __syncthreads();

    // ---- layer 2: waves 0-2, M-tile = wv ----
    if (wv < 3) {
        int mt = wv;
        float bv2 = b2[l & 15];
        f32x4 acc = {bv2, bv2, bv2, bv2};
        #pragma unroll
        for (int ks = 0; ks < 2; ++ks) {
            bf16x8 a = *(const bf16x8*)&sH[((((mt << 1) + ks) << 6) + l) << 3];
            acc = __builtin_amdgcn_mfma_f32_16x16x32_bf16(a, w2f[ks], acc, 0, 0, 0);
        }
        size_t obase = ((size_t)triple * NN + (mt << 4) + ((l >> 4) << 2)) * 16 + (l & 15);
        #pragma unroll
        for (int rg = 0; rg < 4; ++rg)
            out3[obase + (size_t)rg * 16] = sigmoidf_(acc[rg]);
    }
}

extern "C" void kernel_launch(void* const* d_in, const int* in_sizes, int n_in,
                              void* d_out, int out_size, void* d_ws, size_t ws_size,
                              hipStream_t stream) {
    const float* x0 = (const float*)d_in[0];
    const float* x1 = (const float*)d_in[1];
    const float* x2 = (const float*)d_in[2];
    const float* x3 = (const float*)d_in[3];
    const float* W1_0 = (const float*)d_in[4];
    const float* b1_0 = (const float*)d_in[5];
    const float* W2_0 = (const float*)d_in[6];
    const float* b2_0 = (const float*)d_in[7];
    const float* W1_1 = (const float*)d_in[8];
    const float* b1_1 = (const float*)d_in[9];
    const float* W2_1 = (const float*)d_in[10];
    const float* b2_1 = (const float*)d_in[11];
    const float* W1_2 = (const float*)d_in[12];
    const float* b1_2 = (const float*)d_in[13];
    const float* W2_2 = (const float*)d_in[14];
    const float* b2_2 = (const float*)d_in[15];
    const float* W1_3 = (const float*)d_in[16];
    const float* b1_3 = (const float*)d_in[17];
    const float* W2_3 = (const float*)d_in[18];
    const float* b2_3 = (const float*)d_in[19];

    float* out = (float*)d_out;
    float* r3 = (float*)d_ws;                               // 294912 floats
    unsigned short* wf = (unsigned short*)(r3 + 294912);    // 13312 bf16

    hipLaunchKernelGGL(k_pre, dim3(145), dim3(256), 0, stream, x3, W1_3, W2_3, r3, wf);
    hipLaunchKernelGGL(k_small, dim3(625), dim3(256), 0, stream,
                       x0, x1, x2, r3,
                       W1_0, b1_0, W2_0, b2_0,
                       W1_1, b1_1, W2_1, b2_1,
                       W1_2, b1_2, W2_2, b2_2,
                       out);
    hipLaunchKernelGGL(k_g3m, dim3(9216), dim3(256), 0, stream, x2, x3, wf, b1_3, b2_3, out + 150592);
}

// Round 8
// 90.966 us; speedup vs baseline: 7.7755x; 1.0337x over previous
//
#include <hip/hip_runtime.h>
#include <math.h>

#define NN 48

typedef __attribute__((ext_vector_type(8))) short bf16x8;
typedef __attribute__((ext_vector_type(4))) float f32x4;

__device__ __forceinline__ float sigmoidf_(float x) {
    return 1.0f / (1.0f + __expf(-x));
}

__device__ __forceinline__ unsigned short f2bf(float f) {
    unsigned u = __float_as_uint(f);
    return (unsigned short)((u + 0x7fffu + ((u >> 16) & 1u)) >> 16);
}

__device__ __forceinline__ unsigned packbf2(float a, float b) {
    return (unsigned)f2bf(a) | ((unsigned)f2bf(b) << 16);
}

// ================= kernel A (k_pre): round-4-verified weight prep + reduce3 =================
__global__ __launch_bounds__(256) void k_pre(const float* __restrict__ x3,
                                             const float* __restrict__ W1, const float* __restrict__ W2,
                                             float* __restrict__ r3, unsigned short* __restrict__ wf) {
    int tid = threadIdx.x;
    if (blockIdx.x == 0) {
        for (int e = tid; e < 13312; e += 256) {
            unsigned short v;
            if (e < 12288) {
                int idx = e & 7, l = (e >> 3) & 63, r = e >> 9;   // r = nt*6+ks
                int ks = r % 6, nt = r / 6;
                v = f2bf(W1[(ks * 32 + ((l >> 4) << 3) + idx) * 64 + (nt << 4) + (l & 15)]);
            } else {
                int e2 = e - 12288;
                int idx = e2 & 7, l = (e2 >> 3) & 63, ks = e2 >> 9;
                v = f2bf(W2[(ks * 32 + ((l >> 4) << 3) + idx) * 16 + (l & 15)]);
            }
            wf[e] = v;
        }
        return;
    }
    int idx = (blockIdx.x - 1) * 256 + tid;          // < 36864
    int cq = idx & 3;
    int pos = idx >> 2;                               // (b*48+i)*48+j
    int j = pos % NN;
    int i = (pos / NN) % NN;
    const float* base = x3 + (size_t)pos * NN * 16 + (cq << 2);
    float4 ex = make_float4(0.f, 0.f, 0.f, 0.f);
    float4 fa = make_float4(1.f, 1.f, 1.f, 1.f);
    bool dead = (i == j);
    #pragma unroll 8
    for (int k = 0; k < NN; ++k) {
        float4 v = *(const float4*)(base + k * 16);
        bool ok = !dead && (k != i) && (k != j);
        ex.x = fmaxf(ex.x, ok ? v.x : 0.f);  fa.x = fminf(fa.x, ok ? v.x : 1.f);
        ex.y = fmaxf(ex.y, ok ? v.y : 0.f);  fa.y = fminf(fa.y, ok ? v.y : 1.f);
        ex.z = fmaxf(ex.z, ok ? v.z : 0.f);  fa.z = fminf(fa.z, ok ? v.z : 1.f);
        ex.w = fmaxf(ex.w, ok ? v.w : 0.f);  fa.w = fminf(fa.w, ok ? v.w : 1.f);
    }
    float* dst = r3 + (size_t)pos * 32 + (cq << 3);
    *(float4*)dst       = make_float4(ex.x, fa.x, ex.y, fa.y);
    *(float4*)(dst + 4) = make_float4(ex.z, fa.z, ex.w, fa.w);
}

// ================= kernel A2 (k_conv): fp32 -> bf16 copies of x2, x3 =================
// float4-chunk ids: x2 = 36864 chunks (147456 floats), x3 = 1769472 chunks (7077888 floats).
// Total 1806336 chunks = 1764 blocks x 256 threads x 4 iters exactly.
__global__ __launch_bounds__(256) void k_conv(const float* __restrict__ x2, const float* __restrict__ x3,
                                              unsigned short* __restrict__ x2bf,
                                              unsigned short* __restrict__ x3bf) {
    int e = blockIdx.x * 256 + threadIdx.x;
    int stride = gridDim.x * 256;
    for (; e < 1806336; e += stride) {
        const float* src;
        unsigned short* dst;
        if (e < 36864) { int off = e << 2;           src = x2 + off; dst = x2bf + off; }
        else           { int off = (e - 36864) << 2; src = x3 + off; dst = x3bf + off; }
        float4 v = *(const float4*)src;
        uint2 pk;
        pk.x = packbf2(v.x, v.y);
        pk.y = packbf2(v.z, v.w);
        *(uint2*)dst = pk;
    }
}

// ================= kernel B: g0 (block 0) + g1 w/ fused reduce2 (1..48) + g2 (49..624) ==========
__global__ __launch_bounds__(256) void k_small(const float* __restrict__ x0, const float* __restrict__ x1,
        const float* __restrict__ x2, const float* __restrict__ r3,
        const float* __restrict__ W1_0, const float* __restrict__ b1_0,
        const float* __restrict__ W2_0, const float* __restrict__ b2_0,
        const float* __restrict__ W1_1, const float* __restrict__ b1_1,
        const float* __restrict__ W2_1, const float* __restrict__ b2_1,
        const float* __restrict__ W1_2, const float* __restrict__ b1_2,
        const float* __restrict__ W2_2, const float* __restrict__ b2_2,
        float* __restrict__ out) {
    __shared__ __align__(16) float smem[8960];
    int tid = threadIdx.x;
    int blk = blockIdx.x;
    if (blk == 0) {
        float* st0 = smem;            // [4][48]
        float* sh0 = smem + 192;      // [4][64]
        int b = tid >> 6, sub = (tid >> 4) & 3, c = tid & 15;
        float ex = -INFINITY, fa = INFINITY;
        for (int ii = sub * 12; ii < sub * 12 + 12; ++ii) {
            float v = x1[(b * NN + ii) * 16 + c];
            ex = fmaxf(ex, v); fa = fminf(fa, v);
        }
        ex = fmaxf(ex, __shfl_xor(ex, 16)); fa = fminf(fa, __shfl_xor(fa, 16));
        ex = fmaxf(ex, __shfl_xor(ex, 32)); fa = fminf(fa, __shfl_xor(fa, 32));
        if (sub == 0) { st0[b * 48 + 16 + 2 * c] = ex; st0[b * 48 + 17 + 2 * c] = fa; }
        if (tid < 64) st0[(tid >> 4) * 48 + (tid & 15)] = x0[tid];
        __syncthreads();
        {
            int bb = tid >> 6, ln = tid & 63;
            float h = b1_0[ln];
            for (int cc = 0; cc < 48; ++cc) h += st0[bb * 48 + cc] * W1_0[cc * 64 + ln];
            sh0[bb * 64 + ln] = fmaxf(h, 0.f);
        }
        __syncthreads();
        if (tid < 64) {
            int bb = tid >> 4, o = tid & 15;
            float acc = b2_0[o];
            for (int tt = 0; tt < 64; ++tt) acc += sh0[bb * 64 + tt] * W2_0[tt * 16 + o];
            out[bb * 16 + o] = sigmoidf_(acc);
        }
    } else if (blk <= 48) {
        int grp = tid >> 6, ln = tid & 63;
        int row = (blk - 1) * 4 + grp;             // b*48+i, < 192
        int b = row / NN, i = row % NN;
        float* sin1 = smem + grp * 64;
        float* sh1  = smem + 256 + grp * 64;
        int c = ln & 15, q = ln >> 4;
        float ex = 0.f, fa = 1.f;
        const float* xb = x2 + (size_t)row * NN * 16 + c;
        for (int jj = q * 12; jj < q * 12 + 12; ++jj) {
            float v = xb[jj * 16];
            bool ok = (jj != i);
            ex = fmaxf(ex, ok ? v : 0.f); fa = fminf(fa, ok ? v : 1.f);
        }
        ex = fmaxf(ex, __shfl_xor(ex, 16)); fa = fminf(fa, __shfl_xor(fa, 16));
        ex = fmaxf(ex, __shfl_xor(ex, 32)); fa = fminf(fa, __shfl_xor(fa, 32));
        if (q == 0) { sin1[32 + 2 * c] = ex; sin1[33 + 2 * c] = fa; }
        if (ln < 16) sin1[ln] = x0[b * 16 + ln];
        else if (ln < 32) sin1[ln] = x1[row * 16 + (ln - 16)];
        __syncthreads();
        float h = b1_1[ln];
        #pragma unroll
        for (int c4 = 0; c4 < 64; c4 += 4) {
            float4 iv = *(const float4*)&sin1[c4];
            h += iv.x * W1_1[(c4 + 0) * 64 + ln] + iv.y * W1_1[(c4 + 1) * 64 + ln]
               + iv.z * W1_1[(c4 + 2) * 64 + ln] + iv.w * W1_1[(c4 + 3) * 64 + ln];
        }
        sh1[ln] = fmaxf(h, 0.f);
        __syncthreads();
        if (ln < 16) {
            float acc = b2_1[ln];
            #pragma unroll
            for (int tt = 0; tt < 64; ++tt) acc += sh1[tt] * W2_1[tt * 16 + ln];
            out[64 + row * 16 + ln] = sigmoidf_(acc);
        }
    } else {
        float* sW1  = smem;            // 8192
        float* sin_ = smem + 8192;     // [4][128]
        float* sh   = smem + 8704;     // [4][64]
        int wv = tid >> 6, ln = tid & 63;
        for (int p = tid; p < 8192; p += 256) sW1[p] = W1_2[p];
        float bias = b1_2[ln];
        __syncthreads();
        for (int rr = 0; rr < 4; ++rr) {
            int row = (blk - 49) * 16 + rr * 4 + wv;   // (b*48+i)*48+j
            int j = row % NN;
            int bi = row / NN;
            int i = bi % NN;
            int b = bi / NN;
            for (int cc = ln; cc < 128; cc += 64) {
                int half = cc >> 6, w = cc & 63;
                int a1 = half ? j : i;
                int a2 = half ? i : j;
                float v;
                if (w < 16)      v = x1[(b * NN + a1) * 16 + w];
                else if (w < 32) v = x2[((b * NN + a1) * NN + a2) * 16 + (w - 16)];
                else             v = r3[((size_t)(b * NN + a1) * NN + a2) * 32 + (w - 32)];
                sin_[wv * 128 + cc] = v;
            }
            __syncthreads();
            float h = bias;
            #pragma unroll
            for (int c4 = 0; c4 < 128; c4 += 4) {
                float4 iv = *(const float4*)&sin_[wv * 128 + c4];
                h += iv.x * sW1[(c4 + 0) * 64 + ln] + iv.y * sW1[(c4 + 1) * 64 + ln]
                   + iv.z * sW1[(c4 + 2) * 64 + ln] + iv.w * sW1[(c4 + 3) * 64 + ln];
            }
            sh[wv * 64 + ln] = fmaxf(h, 0.f);
            __syncthreads();
            if (ln < 16) {
                float acc = b2_2[ln];
                #pragma unroll
                for (int tt = 0; tt < 64; ++tt) acc += sh[wv * 64 + tt] * W2_2[tt * 16 + ln];
                out[3136 + row * 16 + ln] = sigmoidf_(acc);
            }
            __syncthreads();
        }
    }
}

// ================= kernel C (fast): group 3, zero-staging paired MFMA =================
// Block = (pair i<=j, batch b). Each lane's A-fragment element is 16 contiguous bytes of
// bf16, loaded directly from x2bf/x3bf. One base pointer per lane (selected once), integer
// offsets off_[f] + mt*st_[f] (static after unroll). Each fragment feeds both triples
// (i,j) and (j,i) via the chunk involution p1 = {2,4,0,5,1,3}.
__global__ __launch_bounds__(256) void k_g3d(const unsigned short* __restrict__ x2bf,
        const unsigned short* __restrict__ x3bf, const unsigned short* __restrict__ wf,
        const float* __restrict__ b1, const float* __restrict__ b2,
        float* __restrict__ out3) {
    __shared__ __align__(16) unsigned short sH[2][6 * 64 * 8];   // 12 KB

    int tid = threadIdx.x, wv = tid >> 6, l = tid & 63;
    int pp = blockIdx.x, i = 0;
    while (pp >= NN - i) { pp -= NN - i; ++i; }
    int j = i + pp;                               // i <= j
    int b = blockIdx.y;

    bf16x8 w1f[6];
    #pragma unroll
    for (int ks = 0; ks < 6; ++ks)
        w1f[ks] = *(const bf16x8*)(wf + (((wv * 6 + ks) << 6) + l) * 8);
    bf16x8 w2f[2];
    #pragma unroll
    for (int ks = 0; ks < 2; ++ks)
        w2f[ks] = *(const bf16x8*)(wf + 12288 + ((ks << 6) + l) * 8);

    const int b2b = b * 36864;                    // b*48*48*16
    const int b3b = b * 1769472;                  // b*48*48*48*16
    // chunk order (triple (i,j)): c0=(i,j,k) c1=(i,k,j) c2=(j,i,k) c3=(k,i,j) c4=(j,k,i) c5=(k,j,i)
    const int cb2_[6] = { b2b + (i * NN + j) * 16, b2b + i * 768, b2b + (j * NN + i) * 16,
                          b2b + i * 16,            b2b + j * 768, b2b + j * 16 };
    const int cb3_[6] = { b3b + (i * NN + j) * 768, b3b + i * 36864 + j * 16, b3b + (j * NN + i) * 768,
                          b3b + i * 768 + j * 16,   b3b + j * 36864 + i * 16, b3b + j * 768 + i * 16 };
    const int s2_[6] = { 0, 16, 0, 768, 16, 768 };          // per-kk element stride in x2bf
    const int s3_[6] = { 16, 768, 16, 36864, 768, 36864 };  // per-kk element stride in x3bf

    int l15 = l & 15, g = l >> 4;
    bool isx2 = (g < 2);                          // lanes g=0,1: x2 half; g=2,3: x3 half
    int goff = (g & 1) << 3;
    const unsigned short* bp = isx2 ? x2bf : x3bf;
    int off_[6], st_[6];
    #pragma unroll
    for (int f = 0; f < 6; ++f) {
        int s = isx2 ? s2_[f] : s3_[f];
        int base = isx2 ? cb2_[f] : cb3_[f];
        off_[f] = base + l15 * s + goff;
        st_[f] = s << 4;                          // kk advances by 16 per M-tile
    }

    float bv = b1[(wv << 4) + l15];
    f32x4 acc0_0 = {bv, bv, bv, bv};
    f32x4 acc0_1 = acc0_0, acc0_2 = acc0_0;
    f32x4 acc1_0 = acc0_0, acc1_1 = acc0_0, acc1_2 = acc0_0;
    const int p1[6] = { 2, 4, 0, 5, 1, 3 };

    #pragma unroll
    for (int mt = 0; mt < 3; ++mt) {
        f32x4 a0 = (mt == 0) ? acc0_0 : (mt == 1) ? acc0_1 : acc0_2;
        f32x4 a1 = (mt == 0) ? acc1_0 : (mt == 1) ? acc1_1 : acc1_2;
        #pragma unroll
        for (int f = 0; f < 6; ++f) {
            bf16x8 a = *(const bf16x8*)(bp + off_[f] + mt * st_[f]);
            a0 = __builtin_amdgcn_mfma_f32_16x16x32_bf16(a, w1f[f], a0, 0, 0, 0);
            a1 = __builtin_amdgcn_mfma_f32_16x16x32_bf16(a, w1f[p1[f]], a1, 0, 0, 0);
        }
        if (mt == 0) { acc0_0 = a0; acc1_0 = a1; }
        else if (mt == 1) { acc0_1 = a0; acc1_1 = a1; }
        else { acc0_2 = a0; acc1_2 = a1; }
    }

    // ---- ReLU -> bf16 -> sH (layer-2 A-fragment order), both triples ----
    {
        int within = ((wv & 1) << 4) + l15;        // hc & 31
        int ks2 = wv >> 1;                         // hc >> 5
        int lhi = (within >> 3) << 4;
        int idx = within & 7;
        int rbase = (l >> 4) << 2;
        #pragma unroll
        for (int tr = 0; tr < 2; ++tr) {
            #pragma unroll
            for (int mt = 0; mt < 3; ++mt) {
                f32x4 a = tr ? ((mt == 0) ? acc1_0 : (mt == 1) ? acc1_1 : acc1_2)
                             : ((mt == 0) ? acc0_0 : (mt == 1) ? acc0_1 : acc0_2);
                #pragma unroll
                for (int rg = 0; rg < 4; ++rg) {
                    float h = fmaxf(a[rg], 0.0f);
                    int lp = rbase + rg + lhi;
                    sH[tr][((((mt << 1) + ks2) << 6) + lp) * 8 + idx] = f2bf(h);
                }
            }
        }
    }
    __syncthreads();

    // ---- layer 2: waves 0-2, M-tile = wv, both triples ----
    if (wv < 3) {
        float bv2 = b2[l15];
        #pragma unroll
        for (int tr = 0; tr < 2; ++tr) {
            if (tr == 0 || i != j) {
                f32x4 acc = {bv2, bv2, bv2, bv2};
                #pragma unroll
                for (int ks = 0; ks < 2; ++ks) {
                    bf16x8 a = *(const bf16x8*)&sH[tr][((((wv << 1) + ks) << 6) + l) << 3];
                    acc = __builtin_amdgcn_mfma_f32_16x16x32_bf16(a, w2f[ks], acc, 0, 0, 0);
                }
                int triple = tr ? ((b * NN + j) * NN + i) : ((b * NN + i) * NN + j);
                size_t obase = ((size_t)triple * NN + (wv << 4) + ((l >> 4) << 2)) * 16 + l15;
                #pragma unroll
                for (int rg = 0; rg < 4; ++rg)
                    out3[obase + (size_t)rg * 16] = sigmoidf_(acc[rg]);
            }
        }
    }
}

// ================= kernel C (fallback): round-4-verified fp32 staged version =================
__global__ __launch_bounds__(256) void k_g3m(const float* __restrict__ x2, const float* __restrict__ x3,
                                             const unsigned short* __restrict__ wf,
                                             const float* __restrict__ b1, const float* __restrict__ b2,
                                             float* __restrict__ out3) {
    __shared__ __align__(16) unsigned short sA[18 * 64 * 8];
    __shared__ __align__(16) unsigned short sH[6 * 64 * 8];

    int tid = threadIdx.x;
    int wv = tid >> 6, l = tid & 63;
    int triple = blockIdx.x;
    int j = triple % NN;
    int bi = triple / NN;
    int i = bi % NN;
    int b = bi / NN;

    bf16x8 w1f[6];
    #pragma unroll
    for (int ks = 0; ks < 6; ++ks)
        w1f[ks] = *(const bf16x8*)(wf + (((wv * 6 + ks) << 6) + l) * 8);
    bf16x8 w2f[2];
    #pragma unroll
    for (int ks = 0; ks < 2; ++ks)
        w2f[ks] = *(const bf16x8*)(wf + 12288 + ((ks << 6) + l) * 8);

    const int x2b = b * NN * NN * 16;
    const int x3b = b * NN * NN * NN * 16;

    #pragma unroll
    for (int it = 0; it < 9; ++it) {
        int t = it * 256 + tid;
        int fs = __builtin_amdgcn_readfirstlane(t >> 7);
        int mt = fs / 6;
        int ks = fs - mt * 6;
        int lp = (t >> 1) & 63;
        int kk = (mt << 4) + (lp & 15);
        int w = ((lp >> 4) << 3) + ((t & 1) << 2);
        int a1, a2, a3;
        switch (ks) {
            case 0:  a1 = i;  a2 = j;  a3 = kk; break;
            case 1:  a1 = i;  a2 = kk; a3 = j;  break;
            case 2:  a1 = j;  a2 = i;  a3 = kk; break;
            case 3:  a1 = kk; a2 = i;  a3 = j;  break;
            case 4:  a1 = j;  a2 = kk; a3 = i;  break;
            default: a1 = kk; a2 = j;  a3 = i;  break;
        }
        const float* p2 = x2 + x2b + (a1 * NN + a2) * 16 + w;
        const float* p3 = x3 + x3b + ((a1 * NN + a2) * NN + a3) * 16 + (w - 16);
        const float* p = (w < 16) ? p2 : p3;
        float4 v = *(const float4*)p;
        uint2 pk;
        pk.x = packbf2(v.x, v.y);
        pk.y = packbf2(v.z, v.w);
        *(uint2*)&sA[t * 4] = pk;
    }
    __syncthreads();

    float bv = b1[(wv << 4) + (l & 15)];
    f32x4 acc0 = {bv, bv, bv, bv};
    f32x4 acc1 = acc0, acc2 = acc0;
    #pragma unroll
    for (int ks = 0; ks < 6; ++ks) {
        bf16x8 a0  = *(const bf16x8*)&sA[(((0 * 6 + ks) << 6) + l) << 3];
        bf16x8 a1_ = *(const bf16x8*)&sA[(((1 * 6 + ks) << 6) + l) << 3];
        bf16x8 a2_ = *(const bf16x8*)&sA[(((2 * 6 + ks) << 6) + l) << 3];
        acc0 = __builtin_amdgcn_mfma_f32_16x16x32_bf16(a0,  w1f[ks], acc0, 0, 0, 0);
        acc1 = __builtin_amdgcn_mfma_f32_16x16x32_bf16(a1_, w1f[ks], acc1, 0, 0, 0);
        acc2 = __builtin_amdgcn_mfma_f32_16x16x32_bf16(a2_, w1f[ks], acc2, 0, 0, 0);
    }

    {
        int within = ((wv & 1) << 4) + (l & 15);
        int ks2 = wv >> 1;
        int lhi = (within >> 3) << 4;
        int idx = within & 7;
        int rbase = (l >> 4) << 2;
        #pragma unroll
        for (int mt = 0; mt < 3; ++mt) {
            f32x4 a = (mt == 0) ? acc0 : (mt == 1) ? acc1 : acc2;
            #pragma unroll
            for (int rg = 0; rg < 4; ++rg) {
                float h = fmaxf(a[rg], 0.0f);
                int lp = rbase + rg + lhi;
                sH[((((mt << 1) + ks2) << 6) + lp) * 8 + idx] = f2bf(h);
            }
        }
    }
    __syncthreads();

    if (wv < 3) {
        int mt = wv;
        float bv2 = b2[l & 15];
        f32x4 acc = {bv2, bv2, bv2, bv2};
        #pragma unroll
        for (int ks = 0; ks < 2; ++ks) {
            bf16x8 a = *(const bf16x8*)&sH[((((mt << 1) + ks) << 6) + l) << 3];
            acc = __builtin_amdgcn_mfma_f32_16x16x32_bf16(a, w2f[ks], acc, 0, 0, 0);
        }
        size_t obase = ((size_t)triple * NN + (mt << 4) + ((l >> 4) << 2)) * 16 + (l & 15);
        #pragma unroll
        for (int rg = 0; rg < 4; ++rg)
            out3[obase + (size_t)rg * 16] = sigmoidf_(acc[rg]);
    }
}

extern "C" void kernel_launch(void* const* d_in, const int* in_sizes, int n_in,
                              void* d_out, int out_size, void* d_ws, size_t ws_size,
                              hipStream_t stream) {
    const float* x0 = (const float*)d_in[0];
    const float* x1 = (const float*)d_in[1];
    const float* x2 = (const float*)d_in[2];
    const float* x3 = (const float*)d_in[3];
    const float* W1_0 = (const float*)d_in[4];
    const float* b1_0 = (const float*)d_in[5];
    const float* W2_0 = (const float*)d_in[6];
    const float* b2_0 = (const float*)d_in[7];
    const float* W1_1 = (const float*)d_in[8];
    const float* b1_1 = (const float*)d_in[9];
    const float* W2_1 = (const float*)d_in[10];
    const float* b2_1 = (const float*)d_in[11];
    const float* W1_2 = (const float*)d_in[12];
    const float* b1_2 = (const float*)d_in[13];
    const float* W2_2 = (const float*)d_in[14];
    const float* b2_2 = (const float*)d_in[15];
    const float* W1_3 = (const float*)d_in[16];
    const float* b1_3 = (const float*)d_in[17];
    const float* W2_3 = (const float*)d_in[18];
    const float* b2_3 = (const float*)d_in[19];

    float* out = (float*)d_out;
    float* r3 = (float*)d_ws;                               // 294912 f32
    unsigned short* wf   = (unsigned short*)(r3 + 294912);  // 13312 bf16
    unsigned short* x2bf = wf + 13312;                      // 147456 bf16 (x2 element count)
    unsigned short* x3bf = x2bf + 147456;                   // 7077888 bf16 (x3 element count)
    size_t need = (size_t)294912 * 4 + (size_t)(13312 + 147456 + 7077888) * 2;  // ~15.66 MB
    int fast = (ws_size >= need) ? 1 : 0;

    hipLaunchKernelGGL(k_pre, dim3(145), dim3(256), 0, stream, x3, W1_3, W2_3, r3, wf);
    if (fast) {
        hipLaunchKernelGGL(k_conv, dim3(1764), dim3(256), 0, stream, x2, x3, x2bf, x3bf);
        hipLaunchKernelGGL(k_g3d, dim3(1176, 4), dim3(256), 0, stream,
                           x2bf, x3bf, wf, b1_3, b2_3, out + 150592);
    } else {
        hipLaunchKernelGGL(k_g3m, dim3(9216), dim3(256), 0, stream,
                           x2, x3, wf, b1_3, b2_3, out + 150592);
    }
    hipLaunchKernelGGL(k_small, dim3(625), dim3(256), 0, stream,
                       x0, x1, x2, r3,
                       W1_0, b1_0, W2_0, b2_0,
                       W1_1, b1_1, W2_1, b2_1,
                       W1_2, b1_2, W2_2, b2_2,
                       out);
}

// Round 9
// 81.002 us; speedup vs baseline: 8.7320x; 1.1230x over previous
//
#include <hip/hip_runtime.h>
#include <math.h>

#define NN 48

typedef __attribute__((ext_vector_type(8))) short bf16x8;
typedef __attribute__((ext_vector_type(4))) float f32x4;

__device__ __forceinline__ float sigmoidf_(float x) {
    return 1.0f / (1.0f + __expf(-x));
}

__device__ __forceinline__ unsigned short f2bf(float f) {
    unsigned u = __float_as_uint(f);
    return (unsigned short)((u + 0x7fffu + ((u >> 16) & 1u)) >> 16);
}

__device__ __forceinline__ unsigned packbf2(float a, float b) {
    return (unsigned)f2bf(a) | ((unsigned)f2bf(b) << 16);
}

// ================= kernel A (k_pre): fused reduce3 + x3bf emission + x2bf + weights =========
// blocks [0,2304):   reduce3 (4 pos/block, shfl tree over k) + x3->bf16 emission (x3 read ONCE)
// blocks [2304,2340): x2->bf16 (36864 float4 chunks = 36 blocks x 256 x 4)
// block 2340:        W1_3/W2_3 -> bf16 MFMA B-fragments
// r3[pos][2c]=max_{k not in {i,j}} (0-folded), [2c+1]=min (1-folded); i==j -> 0/1.
__global__ __launch_bounds__(256) void k_pre(const float* __restrict__ x2, const float* __restrict__ x3,
        const float* __restrict__ W1, const float* __restrict__ W2,
        float* __restrict__ r3, unsigned short* __restrict__ wf,
        unsigned short* __restrict__ x2bf, unsigned short* __restrict__ x3bf, int emit) {
    int tid = threadIdx.x, blk = blockIdx.x;
    if (blk < 2304) {
        int posl = tid >> 6, l = tid & 63;
        int pos = blk * 4 + posl;              // (b*48+i)*48+j < 9216
        int j = pos % NN, i = (pos / NN) % NN;
        int cq = l & 3, kkb = l >> 2;          // cq: channel quad, kkb: 0..15
        float4 ex = make_float4(0.f, 0.f, 0.f, 0.f);
        float4 fa = make_float4(1.f, 1.f, 1.f, 1.f);
        #pragma unroll
        for (int s = 0; s < 3; ++s) {
            int kk = kkb + s * 16;             // 0..47
            size_t idx = (((size_t)pos * NN + kk) << 4) + (cq << 2);
            float4 v = *(const float4*)(x3 + idx);
            if (emit) {
                uint2 pk;
                pk.x = packbf2(v.x, v.y);
                pk.y = packbf2(v.z, v.w);
                *(uint2*)(x3bf + idx) = pk;
            }
            bool ok = (i != j) && (kk != i) && (kk != j);
            ex.x = fmaxf(ex.x, ok ? v.x : 0.f);  fa.x = fminf(fa.x, ok ? v.x : 1.f);
            ex.y = fmaxf(ex.y, ok ? v.y : 0.f);  fa.y = fminf(fa.y, ok ? v.y : 1.f);
            ex.z = fmaxf(ex.z, ok ? v.z : 0.f);  fa.z = fminf(fa.z, ok ? v.z : 1.f);
            ex.w = fmaxf(ex.w, ok ? v.w : 0.f);  fa.w = fminf(fa.w, ok ? v.w : 1.f);
        }
        // reduce over kkb = lane bits 2..5
        #pragma unroll
        for (int m = 4; m <= 32; m <<= 1) {
            ex.x = fmaxf(ex.x, __shfl_xor(ex.x, m));  fa.x = fminf(fa.x, __shfl_xor(fa.x, m));
            ex.y = fmaxf(ex.y, __shfl_xor(ex.y, m));  fa.y = fminf(fa.y, __shfl_xor(fa.y, m));
            ex.z = fmaxf(ex.z, __shfl_xor(ex.z, m));  fa.z = fminf(fa.z, __shfl_xor(fa.z, m));
            ex.w = fmaxf(ex.w, __shfl_xor(ex.w, m));  fa.w = fminf(fa.w, __shfl_xor(fa.w, m));
        }
        if (kkb == 0) {
            float* dst = r3 + ((size_t)pos << 5) + (cq << 3);
            *(float4*)dst       = make_float4(ex.x, fa.x, ex.y, fa.y);
            *(float4*)(dst + 4) = make_float4(ex.z, fa.z, ex.w, fa.w);
        }
    } else if (blk < 2340) {
        if (!emit) return;
        int bb = blk - 2304;                   // 0..35
        #pragma unroll
        for (int q = 0; q < 4; ++q) {
            int e = bb * 1024 + q * 256 + tid; // float4 chunk < 36864
            int off = e << 2;                  // float offset < 147456
            float4 v = *(const float4*)(x2 + off);
            uint2 pk;
            pk.x = packbf2(v.x, v.y);
            pk.y = packbf2(v.z, v.w);
            *(uint2*)(x2bf + off) = pk;
        }
    } else {
        for (int e = tid; e < 13312; e += 256) {
            unsigned short v;
            if (e < 12288) {
                int idx = e & 7, l = (e >> 3) & 63, r = e >> 9;   // r = nt*6+ks
                int ks = r % 6, nt = r / 6;
                v = f2bf(W1[(ks * 32 + ((l >> 4) << 3) + idx) * 64 + (nt << 4) + (l & 15)]);
            } else {
                int e2 = e - 12288;
                int idx = e2 & 7, l = (e2 >> 3) & 63, ks = e2 >> 9;
                v = f2bf(W2[(ks * 32 + ((l >> 4) << 3) + idx) * 16 + (l & 15)]);
            }
            wf[e] = v;
        }
    }
}

// ================= kernel B: g0 (block 0) + g1 w/ fused reduce2 (1..48) + g2 (49..624) ==========
__global__ __launch_bounds__(256) void k_small(const float* __restrict__ x0, const float* __restrict__ x1,
        const float* __restrict__ x2, const float* __restrict__ r3,
        const float* __restrict__ W1_0, const float* __restrict__ b1_0,
        const float* __restrict__ W2_0, const float* __restrict__ b2_0,
        const float* __restrict__ W1_1, const float* __restrict__ b1_1,
        const float* __restrict__ W2_1, const float* __restrict__ b2_1,
        const float* __restrict__ W1_2, const float* __restrict__ b1_2,
        const float* __restrict__ W2_2, const float* __restrict__ b2_2,
        float* __restrict__ out) {
    __shared__ __align__(16) float smem[8960];
    int tid = threadIdx.x;
    int blk = blockIdx.x;
    if (blk == 0) {
        float* st0 = smem;            // [4][48]
        float* sh0 = smem + 192;      // [4][64]
        int b = tid >> 6, sub = (tid >> 4) & 3, c = tid & 15;
        float ex = -INFINITY, fa = INFINITY;
        for (int ii = sub * 12; ii < sub * 12 + 12; ++ii) {
            float v = x1[(b * NN + ii) * 16 + c];
            ex = fmaxf(ex, v); fa = fminf(fa, v);
        }
        ex = fmaxf(ex, __shfl_xor(ex, 16)); fa = fminf(fa, __shfl_xor(fa, 16));
        ex = fmaxf(ex, __shfl_xor(ex, 32)); fa = fminf(fa, __shfl_xor(fa, 32));
        if (sub == 0) { st0[b * 48 + 16 + 2 * c] = ex; st0[b * 48 + 17 + 2 * c] = fa; }
        if (tid < 64) st0[(tid >> 4) * 48 + (tid & 15)] = x0[tid];
        __syncthreads();
        {
            int bb = tid >> 6, ln = tid & 63;
            float h = b1_0[ln];
            for (int cc = 0; cc < 48; ++cc) h += st0[bb * 48 + cc] * W1_0[cc * 64 + ln];
            sh0[bb * 64 + ln] = fmaxf(h, 0.f);
        }
        __syncthreads();
        if (tid < 64) {
            int bb = tid >> 4, o = tid & 15;
            float acc = b2_0[o];
            for (int tt = 0; tt < 64; ++tt) acc += sh0[bb * 64 + tt] * W2_0[tt * 16 + o];
            out[bb * 16 + o] = sigmoidf_(acc);
        }
    } else if (blk <= 48) {
        int grp = tid >> 6, ln = tid & 63;
        int row = (blk - 1) * 4 + grp;             // b*48+i, < 192
        int b = row / NN, i = row % NN;
        float* sin1 = smem + grp * 64;
        float* sh1  = smem + 256 + grp * 64;
        int c = ln & 15, q = ln >> 4;
        float ex = 0.f, fa = 1.f;
        const float* xb = x2 + (size_t)row * NN * 16 + c;
        for (int jj = q * 12; jj < q * 12 + 12; ++jj) {
            float v = xb[jj * 16];
            bool ok = (jj != i);
            ex = fmaxf(ex, ok ? v : 0.f); fa = fminf(fa, ok ? v : 1.f);
        }
        ex = fmaxf(ex, __shfl_xor(ex, 16)); fa = fminf(fa, __shfl_xor(fa, 16));
        ex = fmaxf(ex, __shfl_xor(ex, 32)); fa = fminf(fa, __shfl_xor(fa, 32));
        if (q == 0) { sin1[32 + 2 * c] = ex; sin1[33 + 2 * c] = fa; }
        if (ln < 16) sin1[ln] = x0[b * 16 + ln];
        else if (ln < 32) sin1[ln] = x1[row * 16 + (ln - 16)];
        __syncthreads();
        float h = b1_1[ln];
        #pragma unroll
        for (int c4 = 0; c4 < 64; c4 += 4) {
            float4 iv = *(const float4*)&sin1[c4];
            h += iv.x * W1_1[(c4 + 0) * 64 + ln] + iv.y * W1_1[(c4 + 1) * 64 + ln]
               + iv.z * W1_1[(c4 + 2) * 64 + ln] + iv.w * W1_1[(c4 + 3) * 64 + ln];
        }
        sh1[ln] = fmaxf(h, 0.f);
        __syncthreads();
        if (ln < 16) {
            float acc = b2_1[ln];
            #pragma unroll
            for (int tt = 0; tt < 64; ++tt) acc += sh1[tt] * W2_1[tt * 16 + ln];
            out[64 + row * 16 + ln] = sigmoidf_(acc);
        }
    } else {
        float* sW1  = smem;            // 8192
        float* sin_ = smem + 8192;     // [4][128]
        float* sh   = smem + 8704;     // [4][64]
        int wv = tid >> 6, ln = tid & 63;
        for (int p = tid; p < 8192; p += 256) sW1[p] = W1_2[p];
        float bias = b1_2[ln];
        __syncthreads();
        for (int rr = 0; rr < 4; ++rr) {
            int row = (blk - 49) * 16 + rr * 4 + wv;   // (b*48+i)*48+j
            int j = row % NN;
            int bi = row / NN;
            int i = bi % NN;
            int b = bi / NN;
            for (int cc = ln; cc < 128; cc += 64) {
                int half = cc >> 6, w = cc & 63;
                int a1 = half ? j : i;
                int a2 = half ? i : j;
                float v;
                if (w < 16)      v = x1[(b * NN + a1) * 16 + w];
                else if (w < 32) v = x2[((b * NN + a1) * NN + a2) * 16 + (w - 16)];
                else             v = r3[((size_t)(b * NN + a1) * NN + a2) * 32 + (w - 32)];
                sin_[wv * 128 + cc] = v;
            }
            __syncthreads();
            float h = bias;
            #pragma unroll
            for (int c4 = 0; c4 < 128; c4 += 4) {
                float4 iv = *(const float4*)&sin_[wv * 128 + c4];
                h += iv.x * sW1[(c4 + 0) * 64 + ln] + iv.y * sW1[(c4 + 1) * 64 + ln]
                   + iv.z * sW1[(c4 + 2) * 64 + ln] + iv.w * sW1[(c4 + 3) * 64 + ln];
            }
            sh[wv * 64 + ln] = fmaxf(h, 0.f);
            __syncthreads();
            if (ln < 16) {
                float acc = b2_2[ln];
                #pragma unroll
                for (int tt = 0; tt < 64; ++tt) acc += sh[wv * 64 + tt] * W2_2[tt * 16 + ln];
                out[3136 + row * 16 + ln] = sigmoidf_(acc);
            }
            __syncthreads();
        }
    }
}

// ================= kernel C (fast): group 3, mt-per-wave paired MFMA =================
// Block = (pair i<=j, batch b), 192 threads = 3 waves. Wave = M-tile mt (16 k-rows).
// Each A-fragment load (16B/lane from bf16 x2bf/x3bf) feeds 8 MFMAs (4 N-tiles x 2 triples)
// via the chunk involution p1 = {2,4,0,5,1,3}. 18 fragment loads/block (was 72 in r8).
__global__ __launch_bounds__(192) void k_g3d(const unsigned short* __restrict__ x2bf,
        const unsigned short* __restrict__ x3bf, const unsigned short* __restrict__ wf,
        const float* __restrict__ b1, const float* __restrict__ b2,
        float* __restrict__ out3) {
    __shared__ __align__(16) unsigned short sH[2][6 * 64 * 8];   // 12 KB

    int tid = threadIdx.x, mt = tid >> 6, l = tid & 63;   // wave = M-tile 0..2
    int pp = blockIdx.x, i = 0;
    while (pp >= NN - i) { pp -= NN - i; ++i; }
    int j = i + pp;                               // i <= j
    int b = blockIdx.y;

    // B fragments: all 4 N-tiles resident (96 VGPR), layer-2 frags (8 VGPR)
    bf16x8 w1f[4][6];
    #pragma unroll
    for (int nt = 0; nt < 4; ++nt)
        #pragma unroll
        for (int ks = 0; ks < 6; ++ks)
            w1f[nt][ks] = *(const bf16x8*)(wf + (((nt * 6 + ks) << 6) + l) * 8);
    bf16x8 w2f[2];
    #pragma unroll
    for (int ks = 0; ks < 2; ++ks)
        w2f[ks] = *(const bf16x8*)(wf + 12288 + ((ks << 6) + l) * 8);

    const int b2b = b * 36864;                    // b*48*48*16
    const int b3b = b * 1769472;                  // b*48*48*48*16
    // chunk order (triple (i,j)): c0=(i,j,k) c1=(i,k,j) c2=(j,i,k) c3=(k,i,j) c4=(j,k,i) c5=(k,j,i)
    const int cb2_[6] = { b2b + (i * NN + j) * 16, b2b + i * 768, b2b + (j * NN + i) * 16,
                          b2b + i * 16,            b2b + j * 768, b2b + j * 16 };
    const int cb3_[6] = { b3b + (i * NN + j) * 768, b3b + i * 36864 + j * 16, b3b + (j * NN + i) * 768,
                          b3b + i * 768 + j * 16,   b3b + j * 36864 + i * 16, b3b + j * 768 + i * 16 };
    const int s2_[6] = { 0, 16, 0, 768, 16, 768 };          // per-k element stride in x2bf
    const int s3_[6] = { 16, 768, 16, 36864, 768, 36864 };  // per-k element stride in x3bf

    int l15 = l & 15, g = l >> 4;
    bool isx2 = (g < 2);                          // lanes g=0,1: x2 chunk half; g=2,3: x3 half
    int goff = (g & 1) << 3;
    const unsigned short* bp = isx2 ? x2bf : x3bf;
    int off_[6];
    #pragma unroll
    for (int f = 0; f < 6; ++f) {
        int s = isx2 ? s2_[f] : s3_[f];
        int base = isx2 ? cb2_[f] : cb3_[f];
        off_[f] = base + ((mt << 4) + l15) * s + goff;   // row = mt*16 + l15
    }

    f32x4 acc[4][2];
    #pragma unroll
    for (int nt = 0; nt < 4; ++nt) {
        float bv = b1[(nt << 4) + l15];
        f32x4 t = {bv, bv, bv, bv};
        acc[nt][0] = t; acc[nt][1] = t;
    }
    const int p1[6] = { 2, 4, 0, 5, 1, 3 };

    #pragma unroll
    for (int f = 0; f < 6; ++f) {
        bf16x8 a = *(const bf16x8*)(bp + off_[f]);
        #pragma unroll
        for (int nt = 0; nt < 4; ++nt) {
            acc[nt][0] = __builtin_amdgcn_mfma_f32_16x16x32_bf16(a, w1f[nt][f], acc[nt][0], 0, 0, 0);
            acc[nt][1] = __builtin_amdgcn_mfma_f32_16x16x32_bf16(a, w1f[nt][p1[f]], acc[nt][1], 0, 0, 0);
        }
    }

    // ---- ReLU -> bf16 -> sH (layer-2 A-fragment order), both triples ----
    {
        int rbase = (l >> 4) << 2;
        #pragma unroll
        for (int tr = 0; tr < 2; ++tr) {
            #pragma unroll
            for (int nt = 0; nt < 4; ++nt) {
                int within = ((nt & 1) << 4) + l15;   // hc & 31
                int ks2 = nt >> 1;                    // hc >> 5
                int lhi = (within >> 3) << 4;
                int idx = within & 7;
                #pragma unroll
                for (int rg = 0; rg < 4; ++rg) {
                    float h = fmaxf(acc[nt][tr][rg], 0.0f);
                    int lp = rbase + rg + lhi;
                    sH[tr][((((mt << 1) + ks2) << 6) + lp) * 8 + idx] = f2bf(h);
                }
            }
        }
    }
    __syncthreads();

    // ---- layer 2: wave mt computes its M-tile, both triples ----
    {
        float bv2 = b2[l15];
        #pragma unroll
        for (int tr = 0; tr < 2; ++tr) {
            if (tr == 0 || i != j) {
                f32x4 acc2 = {bv2, bv2, bv2, bv2};
                #pragma unroll
                for (int ks = 0; ks < 2; ++ks) {
                    bf16x8 a = *(const bf16x8*)&sH[tr][((((mt << 1) + ks) << 6) + l) << 3];
                    acc2 = __builtin_amdgcn_mfma_f32_16x16x32_bf16(a, w2f[ks], acc2, 0, 0, 0);
                }
                int triple = tr ? ((b * NN + j) * NN + i) : ((b * NN + i) * NN + j);
                size_t obase = ((size_t)triple * NN + (mt << 4) + ((l >> 4) << 2)) * 16 + l15;
                #pragma unroll
                for (int rg = 0; rg < 4; ++rg)
                    out3[obase + (size_t)rg * 16] = sigmoidf_(acc2[rg]);
            }
        }
    }
}

// ================= kernel C (fallback): round-4-verified fp32 staged version =================
__global__ __launch_bounds__(256) void k_g3m(const float* __restrict__ x2, const float* __restrict__ x3,
                                             const unsigned short* __restrict__ wf,
                                             const float* __restrict__ b1, const float* __restrict__ b2,
                                             float* __restrict__ out3) {
    __shared__ __align__(16) unsigned short sA[18 * 64 * 8];
    __shared__ __align__(16) unsigned short sH[6 * 64 * 8];

    int tid = threadIdx.x;
    int wv = tid >> 6, l = tid & 63;
    int triple = blockIdx.x;
    int j = triple % NN;
    int bi = triple / NN;
    int i = bi % NN;
    int b = bi / NN;

    bf16x8 w1f[6];
    #pragma unroll
    for (int ks = 0; ks < 6; ++ks)
        w1f[ks] = *(const bf16x8*)(wf + (((wv * 6 + ks) << 6) + l) * 8);
    bf16x8 w2f[2];
    #pragma unroll
    for (int ks = 0; ks < 2; ++ks)
        w2f[ks] = *(const bf16x8*)(wf + 12288 + ((ks << 6) + l) * 8);

    const int x2b = b * NN * NN * 16;
    const int x3b = b * NN * NN * NN * 16;

    #pragma unroll
    for (int it = 0; it < 9; ++it) {
        int t = it * 256 + tid;
        int fs = __builtin_amdgcn_readfirstlane(t >> 7);
        int mt = fs / 6;
        int ks = fs - mt * 6;
        int lp = (t >> 1) & 63;
        int kk = (mt << 4) + (lp & 15);
        int w = ((lp >> 4) << 3) + ((t & 1) << 2);
        int a1, a2, a3;
        switch (ks) {
            case 0:  a1 = i;  a2 = j;  a3 = kk; break;
            case 1:  a1 = i;  a2 = kk; a3 = j;  break;
            case 2:  a1 = j;  a2 = i;  a3 = kk; break;
            case 3:  a1 = kk; a2 = i;  a3 = j;  break;
            case 4:  a1 = j;  a2 = kk; a3 = i;  break;
            default: a1 = kk; a2 = j;  a3 = i;  break;
        }
        const float* p2 = x2 + x2b + (a1 * NN + a2) * 16 + w;
        const float* p3 = x3 + x3b + ((a1 * NN + a2) * NN + a3) * 16 + (w - 16);
        const float* p = (w < 16) ? p2 : p3;
        float4 v = *(const float4*)p;
        uint2 pk;
        pk.x = packbf2(v.x, v.y);
        pk.y = packbf2(v.z, v.w);
        *(uint2*)&sA[t * 4] = pk;
    }
    __syncthreads();

    float bv = b1[(wv << 4) + (l & 15)];
    f32x4 acc0 = {bv, bv, bv, bv};
    f32x4 acc1 = acc0, acc2 = acc0;
    #pragma unroll
    for (int ks = 0; ks < 6; ++ks) {
        bf16x8 a0  = *(const bf16x8*)&sA[(((0 * 6 + ks) << 6) + l) << 3];
        bf16x8 a1_ = *(const bf16x8*)&sA[(((1 * 6 + ks) << 6) + l) << 3];
        bf16x8 a2_ = *(const bf16x8*)&sA[(((2 * 6 + ks) << 6) + l) << 3];
        acc0 = __builtin_amdgcn_mfma_f32_16x16x32_bf16(a0,  w1f[ks], acc0, 0, 0, 0);
        acc1 = __builtin_amdgcn_mfma_f32_16x16x32_bf16(a1_, w1f[ks], acc1, 0, 0, 0);
        acc2 = __builtin_amdgcn_mfma_f32_16x16x32_bf16(a2_, w1f[ks], acc2, 0, 0, 0);
    }

    {
        int within = ((wv & 1) << 4) + (l & 15);
        int ks2 = wv >> 1;
        int lhi = (within >> 3) << 4;
        int idx = within & 7;
        int rbase = (l >> 4) << 2;
        #pragma unroll
        for (int mt = 0; mt < 3; ++mt) {
            f32x4 a = (mt == 0) ? acc0 : (mt == 1) ? acc1 : acc2;
            #pragma unroll
            for (int rg = 0; rg < 4; ++rg) {
                float h = fmaxf(a[rg], 0.0f);
                int lp = rbase + rg + lhi;
                sH[((((mt << 1) + ks2) << 6) + lp) * 8 + idx] = f2bf(h);
            }
        }
    }
    __syncthreads();

    if (wv < 3) {
        int mt = wv;
        float bv2 = b2[l & 15];
        f32x4 acc = {bv2, bv2, bv2, bv2};
        #pragma unroll
        for (int ks = 0; ks < 2; ++ks) {
            bf16x8 a = *(const bf16x8*)&sH[((((mt << 1) + ks) << 6) + l) << 3];
            acc = __builtin_amdgcn_mfma_f32_16x16x32_bf16(a, w2f[ks], acc, 0, 0, 0);
        }
        size_t obase = ((size_t)triple * NN + (mt << 4) + ((l >> 4) << 2)) * 16 + (l & 15);
        #pragma unroll
        for (int rg = 0; rg < 4; ++rg)
            out3[obase + (size_t)rg * 16] = sigmoidf_(acc[rg]);
    }
}

extern "C" void kernel_launch(void* const* d_in, const int* in_sizes, int n_in,
                              void* d_out, int out_size, void* d_ws, size_t ws_size,
                              hipStream_t stream) {
    const float* x0 = (const float*)d_in[0];
    const float* x1 = (const float*)d_in[1];
    const float* x2 = (const float*)d_in[2];
    const float* x3 = (const float*)d_in[3];
    const float* W1_0 = (const float*)d_in[4];
    const float* b1_0 = (const float*)d_in[5];
    const float* W2_0 = (const float*)d_in[6];
    const float* b2_0 = (const float*)d_in[7];
    const float* W1_1 = (const float*)d_in[8];
    const float* b1_1 = (const float*)d_in[9];
    const float* W2_1 = (const float*)d_in[10];
    const float* b2_1 = (const float*)d_in[11];
    const float* W1_2 = (const float*)d_in[12];
    const float* b1_2 = (const float*)d_in[13];
    const float* W2_2 = (const float*)d_in[14];
    const float* b2_2 = (const float*)d_in[15];
    const float* W1_3 = (const float*)d_in[16];
    const float* b1_3 = (const float*)d_in[17];
    const float* W2_3 = (const float*)d_in[18];
    const float* b2_3 = (const float*)d_in[19];

    float* out = (float*)d_out;
    float* r3 = (float*)d_ws;                               // 294912 f32
    unsigned short* wf   = (unsigned short*)(r3 + 294912);  // 13312 bf16
    unsigned short* x2bf = wf + 13312;                      // 147456 bf16
    unsigned short* x3bf = x2bf + 147456;                   // 7077888 bf16
    size_t need = (size_t)294912 * 4 + (size_t)(13312 + 147456 + 7077888) * 2;  // ~15.66 MB
    int fast = (ws_size >= need) ? 1 : 0;

    hipLaunchKernelGGL(k_pre, dim3(2341), dim3(256), 0, stream,
                       x2, x3, W1_3, W2_3, r3, wf, x2bf, x3bf, fast);
    if (fast)
        hipLaunchKernelGGL(k_g3d, dim3(1176, 4), dim3(192), 0, stream,
                           x2bf, x3bf, wf, b1_3, b2_3, out + 150592);
    else
        hipLaunchKernelGGL(k_g3m, dim3(9216), dim3(256), 0, stream,
                           x2, x3, wf, b1_3, b2_3, out + 150592);
    hipLaunchKernelGGL(k_small, dim3(625), dim3(256), 0, stream,
                       x0, x1, x2, r3,
                       W1_0, b1_0, W2_0, b2_0,
                       W1_1, b1_1, W2_1, b2_1,
                       W1_2, b1_2, W2_2, b2_2,
                       out);
}